// Round 4
// baseline (299.329 us; speedup 1.0000x reference)
//
#include <hip/hip_runtime.h>
#include <math.h>

// Problem constants (MultiQueryAttention_20229295964202)
#define BATCH   4
#define SEQQ    2048
#define SEQK    2048
#define DMODEL  512
#define NHEADS  8
#define PDIM    64

typedef __attribute__((ext_vector_type(8))) short short8;   // 8 bf16 (4 VGPRs)
typedef __attribute__((ext_vector_type(4))) float f32x4;    // MFMA C/D frag

__device__ __forceinline__ unsigned short f2bf(float x) {   // RNE
    unsigned u = __builtin_bit_cast(unsigned, x);
    u += 0x7fffu + ((u >> 16) & 1u);
    return (unsigned short)(u >> 16);
}
// pack two fp32 -> 2xbf16 in one dword, round-half-up
__device__ __forceinline__ unsigned pack_bf16_rh(float lo, float hi) {
    unsigned ul = __builtin_bit_cast(unsigned, lo) + 0x8000u;
    unsigned uh = __builtin_bit_cast(unsigned, hi) + 0x8000u;
    return __builtin_amdgcn_perm(uh, ul, 0x07060302u);  // [uh.hi16 : ul.hi16]
}

// ---------------------------------------------------------------------------
// One-time conversion: X (query pre-scaled by 0.125, store) fp32->bf16,
// weights fp32 -> bf16 TRANSPOSED Wt[mat][n][k] (mat 0-7=Wq heads, 8=Wk,
// 9=Wv, 10=Wo).
// ---------------------------------------------------------------------------
__global__ __launch_bounds__(256) void convert_kernel(
    const float* __restrict__ query, const float* __restrict__ store,
    const float* __restrict__ Wq, const float* __restrict__ Wk,
    const float* __restrict__ Wv, const float* __restrict__ Wo,
    unsigned short* __restrict__ Xq, unsigned short* __restrict__ Xs,
    unsigned short* __restrict__ Wt)
{
    const int tid = threadIdx.x;
    const int blk = blockIdx.x;
    if (blk < 4096) {
        const float* src; unsigned short* dst; float sc; int idx;
        if (blk < 2048) { src = query; dst = Xq; sc = 0.125f; idx = (blk * 256 + tid) * 8; }
        else { src = store; dst = Xs; sc = 1.0f; idx = ((blk - 2048) * 256 + tid) * 8; }
        float4 a = *(const float4*)(src + idx);
        float4 b = *(const float4*)(src + idx + 4);
        ushort4 o0, o1;
        o0.x = f2bf(a.x * sc); o0.y = f2bf(a.y * sc);
        o0.z = f2bf(a.z * sc); o0.w = f2bf(a.w * sc);
        o1.x = f2bf(b.x * sc); o1.y = f2bf(b.y * sc);
        o1.z = f2bf(b.z * sc); o1.w = f2bf(b.w * sc);
        *(ushort4*)(dst + idx) = o0;
        *(ushort4*)(dst + idx + 4) = o1;
    } else {
        int widx = (blk - 4096) * 256 + tid;       // 0..45055
        int e = widx * 8;
        int mat = e >> 15;
        int rem = e & 32767;                       // k*64 + n, n aligned to 8
        int k = rem >> 6, n = rem & 63;
        const float* src = (mat < 8) ? (Wq + (size_t)mat * 32768 + rem)
                         : (mat == 8) ? (Wk + rem)
                         : (mat == 9) ? (Wv + rem) : (Wo + rem);
        float4 a = *(const float4*)(src);
        float4 b = *(const float4*)(src + 4);
        unsigned short* d = Wt + (size_t)mat * 32768 + k;
        d[(size_t)(n + 0) * 512] = f2bf(a.x); d[(size_t)(n + 1) * 512] = f2bf(a.y);
        d[(size_t)(n + 2) * 512] = f2bf(a.z); d[(size_t)(n + 3) * 512] = f2bf(a.w);
        d[(size_t)(n + 4) * 512] = f2bf(b.x); d[(size_t)(n + 5) * 512] = f2bf(b.y);
        d[(size_t)(n + 6) * 512] = f2bf(b.z); d[(size_t)(n + 7) * 512] = f2bf(b.w);
    }
}

// ---------------------------------------------------------------------------
// bf16 MFMA GEMM mainloop with register prefetch of the next K-chunk:
// acc[4] (wave strip 16 rows x 64 cols) for Y[64x64] = X[64x512] @ Wt^T.
// ---------------------------------------------------------------------------
struct ProjSmem {
    unsigned short Xt[64 * 72];
    unsigned short Wtile[64 * 72];
};

__device__ __forceinline__ void mfma_gemm_512(const unsigned short* __restrict__ X,
                                              const unsigned short* __restrict__ W,
                                              ProjSmem& sm, f32x4 acc[4])
{
    const int tid = threadIdx.x;
    const int wv = tid >> 6;
    const int lane = tid & 63;
    const int g = lane >> 4;
    const int c16 = lane & 15;

    int r[2], c[2];
    uint4 xreg[2], wreg[2];
#pragma unroll
    for (int it = 0; it < 2; ++it) {
        int flat = tid * 8 + 2048 * it;
        r[it] = flat >> 6; c[it] = flat & 63;
        xreg[it] = *(const uint4*)(X + (size_t)r[it] * 512 + c[it]);
        wreg[it] = *(const uint4*)(W + (size_t)r[it] * 512 + c[it]);
    }

    for (int k0 = 0; k0 < 512; k0 += 64) {
        __syncthreads();   // previous chunk's MFMA reads done
#pragma unroll
        for (int it = 0; it < 2; ++it) {
            *(uint4*)(&sm.Xt[r[it] * 72 + c[it]]) = xreg[it];
            *(uint4*)(&sm.Wtile[r[it] * 72 + c[it]]) = wreg[it];
        }
        if (k0 + 64 < 512) {   // prefetch next chunk (latency hidden by compute)
#pragma unroll
            for (int it = 0; it < 2; ++it) {
                xreg[it] = *(const uint4*)(X + (size_t)r[it] * 512 + k0 + 64 + c[it]);
                wreg[it] = *(const uint4*)(W + (size_t)r[it] * 512 + k0 + 64 + c[it]);
            }
        }
        __syncthreads();
#pragma unroll
        for (int ks = 0; ks < 2; ++ks) {
            short8 aX = *(const short8*)(&sm.Xt[(16 * wv + c16) * 72 + 32 * ks + 8 * g]);
#pragma unroll
            for (int u = 0; u < 4; ++u) {
                short8 bW = *(const short8*)(&sm.Wtile[(16 * u + c16) * 72 + 32 * ks + 8 * g]);
                acc[u] = __builtin_amdgcn_mfma_f32_16x16x32_bf16(aX, bW, acc[u], 0, 0, 0);
            }
        }
    }
}

// ---------------------------------------------------------------------------
// QKV projection (bf16 MFMA). grid = (128, 10).
// ---------------------------------------------------------------------------
__global__ __launch_bounds__(256) void qkv_proj_kernel(
    const unsigned short* __restrict__ Xq, const unsigned short* __restrict__ Xs,
    const unsigned short* __restrict__ Wt,
    const float* __restrict__ bq, const float* __restrict__ bk,
    const float* __restrict__ bv,
    unsigned short* __restrict__ Qbuf, unsigned short* __restrict__ Kbuf,
    unsigned short* __restrict__ Vtbuf)
{
    __shared__ ProjSmem sm;
    const int mat = blockIdx.y;
    const int row0 = blockIdx.x * 64;
    const int b = row0 >> 11;
    const int s0 = row0 & 2047;

    const unsigned short* X = ((mat < NHEADS) ? Xq : Xs) + (size_t)row0 * 512;
    const unsigned short* W = Wt + (size_t)mat * 32768;

    f32x4 z = {0.f, 0.f, 0.f, 0.f};
    f32x4 acc[4] = {z, z, z, z};
    mfma_gemm_512(X, W, sm, acc);

    const int tid = threadIdx.x;
    const int wv = tid >> 6, lane = tid & 63;
    const int g = lane >> 4, c16 = lane & 15;

    if (mat < NHEADS) {
        const float* bias = bq + mat * 64;
        unsigned short* Y = Qbuf + ((size_t)(b * NHEADS + mat) * SEQQ + s0) * PDIM;
#pragma unroll
        for (int u = 0; u < 4; ++u) {
            float bb = 0.125f * bias[16 * u + c16];   // Q pre-scaled
#pragma unroll
            for (int rr = 0; rr < 4; ++rr)
                Y[(size_t)(16 * wv + 4 * g + rr) * PDIM + 16 * u + c16] = f2bf(acc[u][rr] + bb);
        }
    } else if (mat == NHEADS) {
        unsigned short* Y = Kbuf + (size_t)row0 * PDIM;
#pragma unroll
        for (int u = 0; u < 4; ++u) {
            float bb = bk[16 * u + c16];
#pragma unroll
            for (int rr = 0; rr < 4; ++rr)
                Y[(size_t)(16 * wv + 4 * g + rr) * PDIM + 16 * u + c16] = f2bf(acc[u][rr] + bb);
        }
    } else {
        unsigned short* Y = Vtbuf + (size_t)b * PDIM * SEQK;
#pragma unroll
        for (int u = 0; u < 4; ++u) {
            float bb = bv[16 * u + c16];
#pragma unroll
            for (int rr = 0; rr < 4; ++rr)
                Y[(size_t)(16 * u + c16) * SEQK + s0 + 16 * wv + 4 * g + rr] = f2bf(acc[u][rr] + bb);
        }
    }
}

// ---------------------------------------------------------------------------
// Output projection: out fp32 = ctx(bf16)[8192x512] @ Wo + bo
// ---------------------------------------------------------------------------
__global__ __launch_bounds__(256) void out_proj_kernel(
    const unsigned short* __restrict__ ctx, const unsigned short* __restrict__ Wt,
    const float* __restrict__ bo, float* __restrict__ out)
{
    __shared__ ProjSmem sm;
    const int row0 = blockIdx.x * 64;
    f32x4 z = {0.f, 0.f, 0.f, 0.f};
    f32x4 acc[4] = {z, z, z, z};
    mfma_gemm_512(ctx + (size_t)row0 * 512, Wt + (size_t)10 * 32768, sm, acc);

    const int tid = threadIdx.x;
    const int wv = tid >> 6, lane = tid & 63;
    const int g = lane >> 4, c16 = lane & 15;
#pragma unroll
    for (int u = 0; u < 4; ++u) {
        float bb = bo[16 * u + c16];
#pragma unroll
        for (int rr = 0; rr < 4; ++rr)
            out[(size_t)(row0 + 16 * wv + 4 * g + rr) * 64 + 16 * u + c16] = acc[u][rr] + bb;
    }
}

// ---------------------------------------------------------------------------
// Flash attention, bf16 MFMA, S^T formulation, max-free softmax, K/V register
// prefetch. grid = (SQ/64, H, B) = 1024 blocks, 256 thr = 4 waves; wave owns
// 16 queries. LDS 27.6 KB (Q stage unioned with Ks) -> 4 blocks/CU resident.
// Per 64-key tile: 8 MFMAs S^T = K.Q^T, in-lane exp/sum (no shuffles),
// P packed to wave-private LDS, 8 MFMAs PV. 2 barriers/iter; next K/V tile
// rides in registers across the whole compute phase.
// ---------------------------------------------------------------------------
__global__ __launch_bounds__(256) void attn_kernel(
    const unsigned short* __restrict__ Qbuf,
    const unsigned short* __restrict__ Kbuf,
    const unsigned short* __restrict__ Vtbuf,
    unsigned short* __restrict__ ctx)
{
    __shared__ unsigned short smem[2 * 64 * 72 + 4 * 16 * 72];  // 27,648 B
    unsigned short* Ks  = smem;             // also Q staging (union)
    unsigned short* Vts = smem + 64 * 72;   // [p][key]
    unsigned short* Ps  = smem + 2 * 64 * 72;

    const int tid = threadIdx.x;
    const int wv = tid >> 6;
    const int lane = tid & 63;
    const int g = lane >> 4;
    const int c16 = lane & 15;
    const int b = blockIdx.z;
    const int h = blockIdx.y;
    const int q0 = blockIdx.x * 64;

    const unsigned short* Kp  = Kbuf  + (size_t)b * SEQK * PDIM;
    const unsigned short* Vtp = Vtbuf + (size_t)b * PDIM * SEQK;

    int rr[2], cc[2];
#pragma unroll
    for (int it = 0; it < 2; ++it) {
        int flat = tid * 8 + 2048 * it;
        rr[it] = flat >> 6; cc[it] = flat & 63;
    }

    // issue tile-0 K/V loads first (latency overlaps Q staging)
    uint4 kreg[2], vreg[2];
#pragma unroll
    for (int it = 0; it < 2; ++it) {
        kreg[it] = *(const uint4*)(Kp + (size_t)rr[it] * PDIM + cc[it]);
        vreg[it] = *(const uint4*)(Vtp + (size_t)rr[it] * SEQK + cc[it]);
    }

    // stage Q tile (64x64) into the Ks region, extract register frags
    const unsigned short* Qp = Qbuf + ((size_t)(b * NHEADS + h) * SEQQ + q0) * PDIM;
#pragma unroll
    for (int it = 0; it < 2; ++it)
        *(uint4*)(&Ks[rr[it] * 72 + cc[it]]) =
            *(const uint4*)(Qp + (size_t)rr[it] * PDIM + cc[it]);
    __syncthreads();
    short8 bQ[2];   // B[k=p][n=query=c16]
#pragma unroll
    for (int ks = 0; ks < 2; ++ks)
        bQ[ks] = *(const short8*)(&Ks[(16 * wv + c16) * 72 + 32 * ks + 8 * g]);

    f32x4 z = {0.f, 0.f, 0.f, 0.f};
    f32x4 oacc[4] = {z, z, z, z};
    float lsum = 0.f;
    unsigned short* PsW = &Ps[wv * 16 * 72];

    for (int t0 = 0; t0 < SEQK; t0 += 64) {
        __syncthreads();   // Q frag reads done / prev iter MFMA reads done
#pragma unroll
        for (int it = 0; it < 2; ++it) {
            *(uint4*)(&Ks[rr[it] * 72 + cc[it]])  = kreg[it];
            *(uint4*)(&Vts[rr[it] * 72 + cc[it]]) = vreg[it];
        }
        if (t0 + 64 < SEQK) {   // prefetch next tile into registers
#pragma unroll
            for (int it = 0; it < 2; ++it) {
                kreg[it] = *(const uint4*)(Kp + (size_t)(t0 + 64 + rr[it]) * PDIM + cc[it]);
                vreg[it] = *(const uint4*)(Vtp + (size_t)rr[it] * SEQK + t0 + 64 + cc[it]);
            }
        }
        __syncthreads();

        // S^T = K_tile . Q^T : A[m=key] = K-frag, B = Q-frag
        f32x4 sa[4] = {z, z, z, z};
#pragma unroll
        for (int ks = 0; ks < 2; ++ks) {
#pragma unroll
            for (int t = 0; t < 4; ++t) {
                short8 aK = *(const short8*)(&Ks[(16 * t + c16) * 72 + 32 * ks + 8 * g]);
                sa[t] = __builtin_amdgcn_mfma_f32_16x16x32_bf16(aK, bQ[ks], sa[t], 0, 0, 0);
            }
        }

        // in-lane exp + sum; pack P into wave-private LDS (b64 writes)
        float ls = 0.f;
#pragma unroll
        for (int t = 0; t < 4; ++t) {
            float p0 = __expf(sa[t][0]);
            float p1 = __expf(sa[t][1]);
            float p2 = __expf(sa[t][2]);
            float p3 = __expf(sa[t][3]);
            ls += (p0 + p1) + (p2 + p3);
            uint2 w2;
            w2.x = pack_bf16_rh(p0, p1);
            w2.y = pack_bf16_rh(p2, p3);
            *(uint2*)(&PsW[c16 * 72 + 16 * t + 4 * g]) = w2;
        }
        lsum += ls;
        short8 aP[2];
#pragma unroll
        for (int ks = 0; ks < 2; ++ks)
            aP[ks] = *(const short8*)(&PsW[c16 * 72 + 32 * ks + 8 * g]);

        // O += P @ V : B[k=key][n=p] from Vt rows
#pragma unroll
        for (int ks = 0; ks < 2; ++ks) {
#pragma unroll
            for (int u = 0; u < 4; ++u) {
                short8 bV = *(const short8*)(&Vts[(16 * u + c16) * 72 + 32 * ks + 8 * g]);
                oacc[u] = __builtin_amdgcn_mfma_f32_16x16x32_bf16(aP[ks], bV, oacc[u], 0, 0, 0);
            }
        }
    }

    // l lives split across the 4 g-lanes of each query column
    lsum += __shfl_xor(lsum, 16);
    lsum += __shfl_xor(lsum, 32);

    // epilogue: O C-layout lane (g,c16): O[query=4g+r][p=16u+c16]
    unsigned short* cp = ctx + ((size_t)(b * SEQQ + q0 + 16 * wv) * DMODEL) + h * PDIM;
#pragma unroll
    for (int r = 0; r < 4; ++r) {
        float lq = __shfl(lsum, 4 * g + r + 16 * 0 + (lane & 15) * 0 + 0 + (c16 & 0));  // placeholder avoided below
        lq = __shfl(lsum, 4 * g + r);   // lane holding query 4g+r's sum has c16 = 4g+r
        float inv = 1.0f / lq;
#pragma unroll
        for (int u = 0; u < 4; ++u)
            cp[(size_t)(4 * g + r) * DMODEL + 16 * u + c16] = f2bf(oacc[u][r] * inv);
    }
}

// ---------------------------------------------------------------------------
extern "C" void kernel_launch(void* const* d_in, const int* in_sizes, int n_in,
                              void* d_out, int out_size, void* d_ws, size_t ws_size,
                              hipStream_t stream) {
    const float* query = (const float*)d_in[0];
    const float* store = (const float*)d_in[1];
    const float* Wq    = (const float*)d_in[2];
    const float* bq    = (const float*)d_in[3];
    const float* Wk    = (const float*)d_in[4];
    const float* bk    = (const float*)d_in[5];
    const float* Wv    = (const float*)d_in[6];
    const float* bv    = (const float*)d_in[7];
    const float* Wo    = (const float*)d_in[8];
    const float* bo    = (const float*)d_in[9];
    float* out = (float*)d_out;

    // workspace (bf16): Xq | Xs | Wt | Qbuf | Kbuf | Vt | ctx  (~34.7 MiB)
    unsigned short* Xq   = (unsigned short*)d_ws;
    unsigned short* Xs   = Xq + (size_t)8192 * 512;
    unsigned short* Wt   = Xs + (size_t)8192 * 512;
    unsigned short* Qbuf = Wt + (size_t)11 * 64 * 512;
    unsigned short* Kbuf = Qbuf + (size_t)BATCH * NHEADS * SEQQ * PDIM;
    unsigned short* Vtbuf = Kbuf + (size_t)BATCH * SEQK * PDIM;
    unsigned short* ctx  = Vtbuf + (size_t)BATCH * PDIM * SEQK;

    convert_kernel<<<4096 + 176, 256, 0, stream>>>(query, store, Wq, Wk, Wv, Wo,
                                                   Xq, Xs, Wt);

    dim3 gProj((BATCH * SEQQ) / 64, NHEADS + 2);
    qkv_proj_kernel<<<gProj, 256, 0, stream>>>(Xq, Xs, Wt, bq, bk, bv,
                                               Qbuf, Kbuf, Vtbuf);

    dim3 gAttn(SEQQ / 64, NHEADS, BATCH);
    attn_kernel<<<gAttn, 256, 0, stream>>>(Qbuf, Kbuf, Vtbuf, ctx);

    out_proj_kernel<<<(BATCH * SEQQ) / 64, 256, 0, stream>>>(ctx, Wt, bo, out);
}

// Round 5
// 251.916 us; speedup vs baseline: 1.1882x; 1.1882x over previous
//
#include <hip/hip_runtime.h>
#include <math.h>

// Problem constants (MultiQueryAttention_20229295964202)
#define BATCH   4
#define SEQQ    2048
#define SEQK    2048
#define DMODEL  512
#define NHEADS  8
#define PDIM    64

typedef __attribute__((ext_vector_type(8))) short short8;   // 8 bf16 (4 VGPRs)
typedef __attribute__((ext_vector_type(4))) float f32x4;    // MFMA C/D frag

__device__ __forceinline__ unsigned short f2bf(float x) {   // RNE
    unsigned u = __builtin_bit_cast(unsigned, x);
    u += 0x7fffu + ((u >> 16) & 1u);
    return (unsigned short)(u >> 16);
}
// pack two fp32 -> 2xbf16 in one dword, round-half-up
__device__ __forceinline__ unsigned pack_bf16_rh(float lo, float hi) {
    unsigned ul = __builtin_bit_cast(unsigned, lo) + 0x8000u;
    unsigned uh = __builtin_bit_cast(unsigned, hi) + 0x8000u;
    return __builtin_amdgcn_perm(uh, ul, 0x07060302u);  // [uh.hi16 : ul.hi16]
}
__device__ __forceinline__ float bf2f(unsigned hi16) {      // hi16 already <<16-aligned
    return __builtin_bit_cast(float, hi16);
}

// ---------------------------------------------------------------------------
// One-time conversion: X (query pre-scaled by 0.125, store) fp32->bf16,
// weights fp32 -> bf16 TRANSPOSED Wt[mat][n][k] (mat 0-7=Wq, 8=Wk, 9=Wv, 10=Wo)
// ---------------------------------------------------------------------------
__global__ __launch_bounds__(256) void convert_kernel(
    const float* __restrict__ query, const float* __restrict__ store,
    const float* __restrict__ Wq, const float* __restrict__ Wk,
    const float* __restrict__ Wv, const float* __restrict__ Wo,
    unsigned short* __restrict__ Xq, unsigned short* __restrict__ Xs,
    unsigned short* __restrict__ Wt)
{
    const int tid = threadIdx.x;
    const int blk = blockIdx.x;
    if (blk < 4096) {
        const float* src; unsigned short* dst; float sc; int idx;
        if (blk < 2048) { src = query; dst = Xq; sc = 0.125f; idx = (blk * 256 + tid) * 8; }
        else { src = store; dst = Xs; sc = 1.0f; idx = ((blk - 2048) * 256 + tid) * 8; }
        float4 a = *(const float4*)(src + idx);
        float4 b = *(const float4*)(src + idx + 4);
        ushort4 o0, o1;
        o0.x = f2bf(a.x * sc); o0.y = f2bf(a.y * sc);
        o0.z = f2bf(a.z * sc); o0.w = f2bf(a.w * sc);
        o1.x = f2bf(b.x * sc); o1.y = f2bf(b.y * sc);
        o1.z = f2bf(b.z * sc); o1.w = f2bf(b.w * sc);
        *(ushort4*)(dst + idx) = o0;
        *(ushort4*)(dst + idx + 4) = o1;
    } else {
        int widx = (blk - 4096) * 256 + tid;       // 0..45055
        int e = widx * 8;
        int mat = e >> 15;
        int rem = e & 32767;                       // k*64 + n, n aligned to 8
        int k = rem >> 6, n = rem & 63;
        const float* src = (mat < 8) ? (Wq + (size_t)mat * 32768 + rem)
                         : (mat == 8) ? (Wk + rem)
                         : (mat == 9) ? (Wv + rem) : (Wo + rem);
        float4 a = *(const float4*)(src);
        float4 b = *(const float4*)(src + 4);
        unsigned short* d = Wt + (size_t)mat * 32768 + k;
        d[(size_t)(n + 0) * 512] = f2bf(a.x); d[(size_t)(n + 1) * 512] = f2bf(a.y);
        d[(size_t)(n + 2) * 512] = f2bf(a.z); d[(size_t)(n + 3) * 512] = f2bf(a.w);
        d[(size_t)(n + 4) * 512] = f2bf(b.x); d[(size_t)(n + 5) * 512] = f2bf(b.y);
        d[(size_t)(n + 6) * 512] = f2bf(b.z); d[(size_t)(n + 7) * 512] = f2bf(b.w);
    }
}

// ---------------------------------------------------------------------------
// bf16 MFMA GEMM mainloop, 128-row tile: acc[2][4] (wave: 2 strips of 16 rows
// x 64 cols) for Y[128x64] = X[128x512] @ Wt^T. Loads are short-lifetime
// (load -> barrier -> store): no cross-barrier registers (R4 spill lesson).
// ---------------------------------------------------------------------------
struct ProjSmem {
    unsigned short Xt[128 * 72];    // 18432 B
    unsigned short Wtile[64 * 72];  //  9216 B
};                                   // 27648 B -> 5 blocks/CU

__device__ __forceinline__ void mfma_gemm_512_r128(const unsigned short* __restrict__ X,
                                                   const unsigned short* __restrict__ W,
                                                   ProjSmem& sm, f32x4 acc[2][4])
{
    const int tid = threadIdx.x;
    const int wv = tid >> 6;
    const int lane = tid & 63;
    const int g = lane >> 4;
    const int c16 = lane & 15;

    for (int k0 = 0; k0 < 512; k0 += 64) {
        uint4 xreg[4], wreg[2];
        int xr[4], xc[4];
#pragma unroll
        for (int it = 0; it < 4; ++it) {
            int flat = tid * 8 + 2048 * it;
            xr[it] = flat >> 6; xc[it] = flat & 63;
            xreg[it] = *(const uint4*)(X + (size_t)xr[it] * 512 + k0 + xc[it]);
        }
#pragma unroll
        for (int it = 0; it < 2; ++it) {
            int flat = tid * 8 + 2048 * it;
            wreg[it] = *(const uint4*)(W + (size_t)(flat >> 6) * 512 + k0 + (flat & 63));
        }
        __syncthreads();   // previous chunk's MFMA reads done
#pragma unroll
        for (int it = 0; it < 4; ++it)
            *(uint4*)(&sm.Xt[xr[it] * 72 + xc[it]]) = xreg[it];
#pragma unroll
        for (int it = 0; it < 2; ++it) {
            int flat = tid * 8 + 2048 * it;
            *(uint4*)(&sm.Wtile[(flat >> 6) * 72 + (flat & 63)]) = wreg[it];
        }
        __syncthreads();
#pragma unroll
        for (int ks = 0; ks < 2; ++ks) {
            short8 aX[2];
#pragma unroll
            for (int y = 0; y < 2; ++y)
                aX[y] = *(const short8*)(&sm.Xt[(32 * wv + 16 * y + c16) * 72 + 32 * ks + 8 * g]);
#pragma unroll
            for (int u = 0; u < 4; ++u) {
                short8 bW = *(const short8*)(&sm.Wtile[(16 * u + c16) * 72 + 32 * ks + 8 * g]);
                acc[0][u] = __builtin_amdgcn_mfma_f32_16x16x32_bf16(aX[0], bW, acc[0][u], 0, 0, 0);
                acc[1][u] = __builtin_amdgcn_mfma_f32_16x16x32_bf16(aX[1], bW, acc[1][u], 0, 0, 0);
            }
        }
    }
}

// ---------------------------------------------------------------------------
// QKV projection (bf16 MFMA). grid = (64, 10).
// ---------------------------------------------------------------------------
__global__ __launch_bounds__(256) void qkv_proj_kernel(
    const unsigned short* __restrict__ Xq, const unsigned short* __restrict__ Xs,
    const unsigned short* __restrict__ Wt,
    const float* __restrict__ bq, const float* __restrict__ bk,
    const float* __restrict__ bv,
    unsigned short* __restrict__ Qbuf, unsigned short* __restrict__ Kbuf,
    unsigned short* __restrict__ Vtbuf)
{
    __shared__ ProjSmem sm;
    const int mat = blockIdx.y;
    const int row0 = blockIdx.x * 128;
    const int b = row0 >> 11;
    const int s0 = row0 & 2047;

    const unsigned short* X = ((mat < NHEADS) ? Xq : Xs) + (size_t)row0 * 512;
    const unsigned short* W = Wt + (size_t)mat * 32768;

    f32x4 z = {0.f, 0.f, 0.f, 0.f};
    f32x4 acc[2][4] = {{z, z, z, z}, {z, z, z, z}};
    mfma_gemm_512_r128(X, W, sm, acc);

    const int tid = threadIdx.x;
    const int wv = tid >> 6, lane = tid & 63;
    const int g = lane >> 4, c16 = lane & 15;

    if (mat < NHEADS) {
        const float* bias = bq + mat * 64;
        unsigned short* Y = Qbuf + ((size_t)(b * NHEADS + mat) * SEQQ + s0) * PDIM;
#pragma unroll
        for (int u = 0; u < 4; ++u) {
            float bb = 0.125f * bias[16 * u + c16];   // Q pre-scaled
#pragma unroll
            for (int y = 0; y < 2; ++y)
#pragma unroll
                for (int rr = 0; rr < 4; ++rr)
                    Y[(size_t)(32 * wv + 16 * y + 4 * g + rr) * PDIM + 16 * u + c16] =
                        f2bf(acc[y][u][rr] + bb);
        }
    } else if (mat == NHEADS) {
        unsigned short* Y = Kbuf + (size_t)row0 * PDIM;
#pragma unroll
        for (int u = 0; u < 4; ++u) {
            float bb = bk[16 * u + c16];
#pragma unroll
            for (int y = 0; y < 2; ++y)
#pragma unroll
                for (int rr = 0; rr < 4; ++rr)
                    Y[(size_t)(32 * wv + 16 * y + 4 * g + rr) * PDIM + 16 * u + c16] =
                        f2bf(acc[y][u][rr] + bb);
        }
    } else {
        unsigned short* Y = Vtbuf + (size_t)b * PDIM * SEQK;
#pragma unroll
        for (int u = 0; u < 4; ++u) {
            float bb = bv[16 * u + c16];
#pragma unroll
            for (int y = 0; y < 2; ++y)
#pragma unroll
                for (int rr = 0; rr < 4; ++rr)
                    Y[(size_t)(16 * u + c16) * SEQK + s0 + 32 * wv + 16 * y + 4 * g + rr] =
                        f2bf(acc[y][u][rr] + bb);
        }
    }
}

// ---------------------------------------------------------------------------
// Output projection: out fp32 = ctx(bf16)[8192x512] @ Wo + bo. grid = 64.
// ---------------------------------------------------------------------------
__global__ __launch_bounds__(256) void out_proj_kernel(
    const unsigned short* __restrict__ ctx, const unsigned short* __restrict__ Wt,
    const float* __restrict__ bo, float* __restrict__ out)
{
    __shared__ ProjSmem sm;
    const int row0 = blockIdx.x * 128;
    f32x4 z = {0.f, 0.f, 0.f, 0.f};
    f32x4 acc[2][4] = {{z, z, z, z}, {z, z, z, z}};
    mfma_gemm_512_r128(ctx + (size_t)row0 * 512, Wt + (size_t)10 * 32768, sm, acc);

    const int tid = threadIdx.x;
    const int wv = tid >> 6, lane = tid & 63;
    const int g = lane >> 4, c16 = lane & 15;
#pragma unroll
    for (int u = 0; u < 4; ++u) {
        float bb = bo[16 * u + c16];
#pragma unroll
        for (int y = 0; y < 2; ++y)
#pragma unroll
            for (int rr = 0; rr < 4; ++rr)
                out[(size_t)(row0 + 32 * wv + 16 * y + 4 * g + rr) * 64 + 16 * u + c16] =
                    acc[y][u][rr] + bb;
    }
}

// ---------------------------------------------------------------------------
// Flash attention, bf16 MFMA, S^T max-free softmax, K-SPLIT x2.
// grid = (SQ/128, H, B*2) = 1024 blocks, 256 thr = 4 waves; wave owns 32
// queries (2 strips). Each block handles 1024 keys, writes UNNORMALIZED O
// (bf16) + l (fp32); combine_kernel merges the two splits.
// LDS 27.6 KB (Q staged over Ks|Vts union) -> 4 blocks/CU resident.
// Loads are short-lifetime (load->barrier->store): no cross-barrier regs.
// ---------------------------------------------------------------------------
__global__ __launch_bounds__(256) void attn_kernel(
    const unsigned short* __restrict__ Qbuf,
    const unsigned short* __restrict__ Kbuf,
    const unsigned short* __restrict__ Vtbuf,
    unsigned short* __restrict__ O0,   // ctx region (split 0)
    unsigned short* __restrict__ O1,   // Xq region  (split 1)
    float* __restrict__ Lbuf)          // Xs region [split][b][h][q]
{
    __shared__ unsigned short smem[128 * 72 + 4 * 16 * 72];  // 27648 B
    unsigned short* Ks  = smem;             // Q staged here first (union)
    unsigned short* Vts = smem + 64 * 72;   // [p][key]
    unsigned short* Ps  = smem + 128 * 72;

    const int tid = threadIdx.x;
    const int wv = tid >> 6;
    const int lane = tid & 63;
    const int g = lane >> 4;
    const int c16 = lane & 15;
    const int split = blockIdx.z & 1;
    const int b = blockIdx.z >> 1;
    const int h = blockIdx.y;
    const int q0 = blockIdx.x * 128;

    // stage Q tile (128x64) over the Ks|Vts union, extract register frags
    const unsigned short* Qp = Qbuf + ((size_t)(b * NHEADS + h) * SEQQ + q0) * PDIM;
#pragma unroll
    for (int it = 0; it < 4; ++it) {
        int flat = tid * 8 + 2048 * it;
        int r = flat >> 6, c = flat & 63;
        *(uint4*)(&smem[r * 72 + c]) = *(const uint4*)(Qp + (size_t)r * PDIM + c);
    }
    __syncthreads();
    short8 bQ[2][2];   // B[k=p][n=query=c16], strips y, k-chunks ks
#pragma unroll
    for (int y = 0; y < 2; ++y)
#pragma unroll
        for (int ks = 0; ks < 2; ++ks)
            bQ[y][ks] = *(const short8*)(&smem[(32 * wv + 16 * y + c16) * 72 + 32 * ks + 8 * g]);

    f32x4 z = {0.f, 0.f, 0.f, 0.f};
    f32x4 oacc[2][4] = {{z, z, z, z}, {z, z, z, z}};
    float lsum[2] = {0.f, 0.f};

    const unsigned short* Kp  = Kbuf  + (size_t)b * SEQK * PDIM;
    const unsigned short* Vtp = Vtbuf + (size_t)b * PDIM * SEQK;
    int rr[2], cc[2];
#pragma unroll
    for (int it = 0; it < 2; ++it) {
        int flat = tid * 8 + 2048 * it;
        rr[it] = flat >> 6; cc[it] = flat & 63;
    }
    unsigned short* PsW = &Ps[wv * 16 * 72];
    const int kbase = split * 1024;

    for (int i = 0; i < 16; ++i) {
        const int t0 = kbase + 64 * i;
        // short-lifetime staging loads (issued here, stored right after barrier)
        uint4 kreg[2], vreg[2];
#pragma unroll
        for (int it = 0; it < 2; ++it) {
            kreg[it] = *(const uint4*)(Kp + (size_t)(t0 + rr[it]) * PDIM + cc[it]);
            vreg[it] = *(const uint4*)(Vtp + (size_t)rr[it] * SEQK + t0 + cc[it]);
        }
        __syncthreads();   // prev iter MFMA reads (or Q frag reads) done
#pragma unroll
        for (int it = 0; it < 2; ++it) {
            *(uint4*)(&Ks[rr[it] * 72 + cc[it]])  = kreg[it];
            *(uint4*)(&Vts[rr[it] * 72 + cc[it]]) = vreg[it];
        }
        __syncthreads();

        // S^T = K_tile . Q^T : A[m=key] = K-frag (shared across strips)
        f32x4 s0a[4] = {z, z, z, z};
        f32x4 s1a[4] = {z, z, z, z};
#pragma unroll
        for (int ks = 0; ks < 2; ++ks) {
#pragma unroll
            for (int t = 0; t < 4; ++t) {
                short8 aK = *(const short8*)(&Ks[(16 * t + c16) * 72 + 32 * ks + 8 * g]);
                s0a[t] = __builtin_amdgcn_mfma_f32_16x16x32_bf16(aK, bQ[0][ks], s0a[t], 0, 0, 0);
                s1a[t] = __builtin_amdgcn_mfma_f32_16x16x32_bf16(aK, bQ[1][ks], s1a[t], 0, 0, 0);
            }
        }

        // in-lane exp + sum; pack P to wave-private LDS (no barrier needed)
        short8 aP[2][2];
#pragma unroll
        for (int y = 0; y < 2; ++y) {
            const f32x4* sc = y ? s1a : s0a;
            float ls = 0.f;
#pragma unroll
            for (int t = 0; t < 4; ++t) {
                float p0 = __expf(sc[t][0]);
                float p1 = __expf(sc[t][1]);
                float p2 = __expf(sc[t][2]);
                float p3 = __expf(sc[t][3]);
                ls += (p0 + p1) + (p2 + p3);
                uint2 w2;
                w2.x = pack_bf16_rh(p0, p1);
                w2.y = pack_bf16_rh(p2, p3);
                *(uint2*)(&PsW[c16 * 72 + 16 * t + 4 * g]) = w2;
            }
            lsum[y] += ls;
#pragma unroll
            for (int ks = 0; ks < 2; ++ks)
                aP[y][ks] = *(const short8*)(&PsW[c16 * 72 + 32 * ks + 8 * g]);
        }

        // O += P @ V : B[k=key][n=p] from Vt rows (shared across strips)
#pragma unroll
        for (int ks = 0; ks < 2; ++ks) {
#pragma unroll
            for (int u = 0; u < 4; ++u) {
                short8 bV = *(const short8*)(&Vts[(16 * u + c16) * 72 + 32 * ks + 8 * g]);
                oacc[0][u] = __builtin_amdgcn_mfma_f32_16x16x32_bf16(aP[0][ks], bV, oacc[0][u], 0, 0, 0);
                oacc[1][u] = __builtin_amdgcn_mfma_f32_16x16x32_bf16(aP[1][ks], bV, oacc[1][u], 0, 0, 0);
            }
        }
    }

    // l lives split across the 4 g-lanes of each query column
#pragma unroll
    for (int y = 0; y < 2; ++y) {
        lsum[y] += __shfl_xor(lsum[y], 16);
        lsum[y] += __shfl_xor(lsum[y], 32);
    }

    // epilogue: UNNORMALIZED O (bf16) + l. Layout [b][q][h*64+p].
    unsigned short* Od = split ? O1 : O0;
#pragma unroll
    for (int y = 0; y < 2; ++y) {
        unsigned short* cp = Od + ((size_t)(b * SEQQ + q0 + 32 * wv + 16 * y) * DMODEL) + h * PDIM;
#pragma unroll
        for (int r = 0; r < 4; ++r) {
#pragma unroll
            for (int u = 0; u < 4; ++u)
                cp[(size_t)(4 * g + r) * DMODEL + 16 * u + c16] = f2bf(oacc[y][u][r]);
        }
        if (g == 0)
            Lbuf[(((size_t)split * BATCH + b) * NHEADS + h) * SEQQ + q0 + 32 * wv + 16 * y + c16] = lsum[y];
    }
}

// ---------------------------------------------------------------------------
// Combine: ctx = (O0 + O1) / (l0 + l1), elementwise over [B,SQ,512].
// grid = 2048 x 256, 8 bf16 per thread.
// ---------------------------------------------------------------------------
__global__ __launch_bounds__(256) void combine_kernel(
    const unsigned short* __restrict__ O1, const float* __restrict__ Lbuf,
    unsigned short* __restrict__ ctx)
{
    int gid = blockIdx.x * 256 + threadIdx.x;   // 524288
    int idx8 = gid * 8;
    int bs = idx8 >> 9;           // b*2048 + s
    int col = idx8 & 511;
    int b = bs >> 11, s = bs & 2047;
    int h = col >> 6;
    uint4 a0 = *(const uint4*)(ctx + idx8);
    uint4 a1 = *(const uint4*)(O1 + idx8);
    float l0 = Lbuf[(((size_t)0 * BATCH + b) * NHEADS + h) * SEQQ + s];
    float l1 = Lbuf[(((size_t)1 * BATCH + b) * NHEADS + h) * SEQQ + s];
    float inv = 1.0f / (l0 + l1);
    const unsigned* u0 = (const unsigned*)&a0;
    const unsigned* u1 = (const unsigned*)&a1;
    uint4 o;
    unsigned* uo = (unsigned*)&o;
#pragma unroll
    for (int j = 0; j < 4; ++j) {
        float lo = (bf2f(u0[j] << 16) + bf2f(u1[j] << 16)) * inv;
        float hi = (bf2f(u0[j] & 0xFFFF0000u) + bf2f(u1[j] & 0xFFFF0000u)) * inv;
        uo[j] = pack_bf16_rh(lo, hi);
    }
    *(uint4*)(ctx + idx8) = o;
}

// ---------------------------------------------------------------------------
extern "C" void kernel_launch(void* const* d_in, const int* in_sizes, int n_in,
                              void* d_out, int out_size, void* d_ws, size_t ws_size,
                              hipStream_t stream) {
    const float* query = (const float*)d_in[0];
    const float* store = (const float*)d_in[1];
    const float* Wq    = (const float*)d_in[2];
    const float* bq    = (const float*)d_in[3];
    const float* Wk    = (const float*)d_in[4];
    const float* bk    = (const float*)d_in[5];
    const float* Wv    = (const float*)d_in[6];
    const float* bv    = (const float*)d_in[7];
    const float* Wo    = (const float*)d_in[8];
    const float* bo    = (const float*)d_in[9];
    float* out = (float*)d_out;

    // workspace (bf16 unless noted), with region reuse:
    // Xq [8192,512]  -- input to qkv; REUSED as O1 (split-1 unnormalized O)
    // Xs [8192,512]  -- input to qkv; REUSED as Lbuf (fp32, 512 KB)
    // Wt [11,64,512] | Qbuf | Kbuf | Vt | ctx [B,SQ,512] (split-0 O, then ctx)
    unsigned short* Xq   = (unsigned short*)d_ws;
    unsigned short* Xs   = Xq + (size_t)8192 * 512;
    unsigned short* Wt   = Xs + (size_t)8192 * 512;
    unsigned short* Qbuf = Wt + (size_t)11 * 64 * 512;
    unsigned short* Kbuf = Qbuf + (size_t)BATCH * NHEADS * SEQQ * PDIM;
    unsigned short* Vtbuf = Kbuf + (size_t)BATCH * SEQK * PDIM;
    unsigned short* ctx  = Vtbuf + (size_t)BATCH * PDIM * SEQK;
    unsigned short* O1   = Xq;              // safe: Xq consumed by qkv_proj
    float* Lbuf          = (float*)Xs;      // safe: Xs consumed by qkv_proj

    convert_kernel<<<4096 + 176, 256, 0, stream>>>(query, store, Wq, Wk, Wv, Wo,
                                                   Xq, Xs, Wt);

    dim3 gProj((BATCH * SEQQ) / 128, NHEADS + 2);
    qkv_proj_kernel<<<gProj, 256, 0, stream>>>(Xq, Xs, Wt, bq, bk, bv,
                                               Qbuf, Kbuf, Vtbuf);

    dim3 gAttn(SEQQ / 128, NHEADS, BATCH * 2);
    attn_kernel<<<gAttn, 256, 0, stream>>>(Qbuf, Kbuf, Vtbuf, ctx, O1, Lbuf);

    combine_kernel<<<2048, 256, 0, stream>>>(O1, Lbuf, ctx);

    out_proj_kernel<<<(BATCH * SEQQ) / 128, 256, 0, stream>>>(ctx, Wt, bo, out);
}

// Round 6
// 227.507 us; speedup vs baseline: 1.3157x; 1.1073x over previous
//
#include <hip/hip_runtime.h>
#include <math.h>

// Problem constants (MultiQueryAttention_20229295964202)
#define BATCH   4
#define SEQQ    2048
#define SEQK    2048
#define DMODEL  512
#define NHEADS  8
#define PDIM    64

typedef __attribute__((ext_vector_type(8))) short short8;   // 8 bf16 (4 VGPRs)
typedef __attribute__((ext_vector_type(4))) float f32x4;    // MFMA C/D frag

__device__ __forceinline__ unsigned short f2bf(float x) {   // RNE
    unsigned u = __builtin_bit_cast(unsigned, x);
    u += 0x7fffu + ((u >> 16) & 1u);
    return (unsigned short)(u >> 16);
}
// pack two fp32 -> 2xbf16 in one dword, round-half-up
__device__ __forceinline__ unsigned pack_bf16_rh(float lo, float hi) {
    unsigned ul = __builtin_bit_cast(unsigned, lo) + 0x8000u;
    unsigned uh = __builtin_bit_cast(unsigned, hi) + 0x8000u;
    return __builtin_amdgcn_perm(uh, ul, 0x07060302u);  // [uh.hi16 : ul.hi16]
}
__device__ __forceinline__ float bf2f_lo(unsigned w) {
    return __builtin_bit_cast(float, w << 16);
}
__device__ __forceinline__ float bf2f_hi(unsigned w) {
    return __builtin_bit_cast(float, w & 0xFFFF0000u);
}

// async global->LDS, 16B/lane; lds base is wave-uniform, HW adds lane*16
__device__ __forceinline__ void glds16(const unsigned short* g, unsigned short* l) {
    __builtin_amdgcn_global_load_lds(
        (const __attribute__((address_space(1))) void*)g,
        (__attribute__((address_space(3))) void*)l, 16, 0, 0);
}

// ---------------------------------------------------------------------------
// One-time conversion: X (query pre-scaled by 0.125, store) fp32->bf16,
// weights fp32 -> bf16 TRANSPOSED Wt[mat][n][k] (mat 0-7=Wq, 8=Wk, 9=Wv, 10=Wo)
// ---------------------------------------------------------------------------
__global__ __launch_bounds__(256) void convert_kernel(
    const float* __restrict__ query, const float* __restrict__ store,
    const float* __restrict__ Wq, const float* __restrict__ Wk,
    const float* __restrict__ Wv, const float* __restrict__ Wo,
    unsigned short* __restrict__ Xq, unsigned short* __restrict__ Xs,
    unsigned short* __restrict__ Wt)
{
    const int tid = threadIdx.x;
    const int blk = blockIdx.x;
    if (blk < 4096) {
        const float* src; unsigned short* dst; float sc; int idx;
        if (blk < 2048) { src = query; dst = Xq; sc = 0.125f; idx = (blk * 256 + tid) * 8; }
        else { src = store; dst = Xs; sc = 1.0f; idx = ((blk - 2048) * 256 + tid) * 8; }
        float4 a = *(const float4*)(src + idx);
        float4 b = *(const float4*)(src + idx + 4);
        ushort4 o0, o1;
        o0.x = f2bf(a.x * sc); o0.y = f2bf(a.y * sc);
        o0.z = f2bf(a.z * sc); o0.w = f2bf(a.w * sc);
        o1.x = f2bf(b.x * sc); o1.y = f2bf(b.y * sc);
        o1.z = f2bf(b.z * sc); o1.w = f2bf(b.w * sc);
        *(ushort4*)(dst + idx) = o0;
        *(ushort4*)(dst + idx + 4) = o1;
    } else {
        int widx = (blk - 4096) * 256 + tid;       // 0..45055
        int e = widx * 8;
        int mat = e >> 15;
        int rem = e & 32767;                       // k*64 + n, n aligned to 8
        int k = rem >> 6, n = rem & 63;
        const float* src = (mat < 8) ? (Wq + (size_t)mat * 32768 + rem)
                         : (mat == 8) ? (Wk + rem)
                         : (mat == 9) ? (Wv + rem) : (Wo + rem);
        float4 a = *(const float4*)(src);
        float4 b = *(const float4*)(src + 4);
        unsigned short* d = Wt + (size_t)mat * 32768 + k;
        d[(size_t)(n + 0) * 512] = f2bf(a.x); d[(size_t)(n + 1) * 512] = f2bf(a.y);
        d[(size_t)(n + 2) * 512] = f2bf(a.z); d[(size_t)(n + 3) * 512] = f2bf(a.w);
        d[(size_t)(n + 4) * 512] = f2bf(b.x); d[(size_t)(n + 5) * 512] = f2bf(b.y);
        d[(size_t)(n + 6) * 512] = f2bf(b.z); d[(size_t)(n + 7) * 512] = f2bf(b.w);
    }
}

// ---------------------------------------------------------------------------
// bf16 MFMA GEMM mainloop, 128-row tile (R5 structure, proven clean).
// ---------------------------------------------------------------------------
struct ProjSmem {
    unsigned short Xt[128 * 72];
    unsigned short Wtile[64 * 72];
};

__device__ __forceinline__ void mfma_gemm_512_r128(const unsigned short* __restrict__ X,
                                                   const unsigned short* __restrict__ W,
                                                   ProjSmem& sm, f32x4 acc[2][4])
{
    const int tid = threadIdx.x;
    const int wv = tid >> 6;
    const int lane = tid & 63;
    const int g = lane >> 4;
    const int c16 = lane & 15;

    for (int k0 = 0; k0 < 512; k0 += 64) {
        uint4 xreg[4], wreg[2];
        int xr[4], xc[4];
#pragma unroll
        for (int it = 0; it < 4; ++it) {
            int flat = tid * 8 + 2048 * it;
            xr[it] = flat >> 6; xc[it] = flat & 63;
            xreg[it] = *(const uint4*)(X + (size_t)xr[it] * 512 + k0 + xc[it]);
        }
#pragma unroll
        for (int it = 0; it < 2; ++it) {
            int flat = tid * 8 + 2048 * it;
            wreg[it] = *(const uint4*)(W + (size_t)(flat >> 6) * 512 + k0 + (flat & 63));
        }
        __syncthreads();
#pragma unroll
        for (int it = 0; it < 4; ++it)
            *(uint4*)(&sm.Xt[xr[it] * 72 + xc[it]]) = xreg[it];
#pragma unroll
        for (int it = 0; it < 2; ++it) {
            int flat = tid * 8 + 2048 * it;
            *(uint4*)(&sm.Wtile[(flat >> 6) * 72 + (flat & 63)]) = wreg[it];
        }
        __syncthreads();
#pragma unroll
        for (int ks = 0; ks < 2; ++ks) {
            short8 aX[2];
#pragma unroll
            for (int y = 0; y < 2; ++y)
                aX[y] = *(const short8*)(&sm.Xt[(32 * wv + 16 * y + c16) * 72 + 32 * ks + 8 * g]);
#pragma unroll
            for (int u = 0; u < 4; ++u) {
                short8 bW = *(const short8*)(&sm.Wtile[(16 * u + c16) * 72 + 32 * ks + 8 * g]);
                acc[0][u] = __builtin_amdgcn_mfma_f32_16x16x32_bf16(aX[0], bW, acc[0][u], 0, 0, 0);
                acc[1][u] = __builtin_amdgcn_mfma_f32_16x16x32_bf16(aX[1], bW, acc[1][u], 0, 0, 0);
            }
        }
    }
}

// ---------------------------------------------------------------------------
// QKV projection (bf16 MFMA). grid = (64, 10).
// ---------------------------------------------------------------------------
__global__ __launch_bounds__(256) void qkv_proj_kernel(
    const unsigned short* __restrict__ Xq, const unsigned short* __restrict__ Xs,
    const unsigned short* __restrict__ Wt,
    const float* __restrict__ bq, const float* __restrict__ bk,
    const float* __restrict__ bv,
    unsigned short* __restrict__ Qbuf, unsigned short* __restrict__ Kbuf,
    unsigned short* __restrict__ Vtbuf)
{
    __shared__ ProjSmem sm;
    const int mat = blockIdx.y;
    const int row0 = blockIdx.x * 128;
    const int b = row0 >> 11;
    const int s0 = row0 & 2047;

    const unsigned short* X = ((mat < NHEADS) ? Xq : Xs) + (size_t)row0 * 512;
    const unsigned short* W = Wt + (size_t)mat * 32768;

    f32x4 z = {0.f, 0.f, 0.f, 0.f};
    f32x4 acc[2][4] = {{z, z, z, z}, {z, z, z, z}};
    mfma_gemm_512_r128(X, W, sm, acc);

    const int tid = threadIdx.x;
    const int wv = tid >> 6, lane = tid & 63;
    const int g = lane >> 4, c16 = lane & 15;

    if (mat < NHEADS) {
        const float* bias = bq + mat * 64;
        unsigned short* Y = Qbuf + ((size_t)(b * NHEADS + mat) * SEQQ + s0) * PDIM;
#pragma unroll
        for (int u = 0; u < 4; ++u) {
            float bb = 0.125f * bias[16 * u + c16];   // Q pre-scaled
#pragma unroll
            for (int y = 0; y < 2; ++y)
#pragma unroll
                for (int rr = 0; rr < 4; ++rr)
                    Y[(size_t)(32 * wv + 16 * y + 4 * g + rr) * PDIM + 16 * u + c16] =
                        f2bf(acc[y][u][rr] + bb);
        }
    } else if (mat == NHEADS) {
        unsigned short* Y = Kbuf + (size_t)row0 * PDIM;
#pragma unroll
        for (int u = 0; u < 4; ++u) {
            float bb = bk[16 * u + c16];
#pragma unroll
            for (int y = 0; y < 2; ++y)
#pragma unroll
                for (int rr = 0; rr < 4; ++rr)
                    Y[(size_t)(32 * wv + 16 * y + 4 * g + rr) * PDIM + 16 * u + c16] =
                        f2bf(acc[y][u][rr] + bb);
        }
    } else {
        unsigned short* Y = Vtbuf + (size_t)b * PDIM * SEQK;
#pragma unroll
        for (int u = 0; u < 4; ++u) {
            float bb = bv[16 * u + c16];
#pragma unroll
            for (int y = 0; y < 2; ++y)
#pragma unroll
                for (int rr = 0; rr < 4; ++rr)
                    Y[(size_t)(16 * u + c16) * SEQK + s0 + 32 * wv + 16 * y + 4 * g + rr] =
                        f2bf(acc[y][u][rr] + bb);
        }
    }
}

// ---------------------------------------------------------------------------
// Flash attention, bf16 MFMA, S^T max-free softmax, K-SPLIT x2.
// glds (async global->LDS) + DOUBLE-BUFFERED K/V + ONE barrier/iter:
// prefetch issued right after the barrier flies across the whole compute
// phase (no registers held -> no spill). XOR column swizzle (chunk ^= row&7,
// stride 64 shorts) since glds needs contiguous rows; frag reads conflict-free.
// Epilogue: raw (unnormalized) bf16-pair-packed O in accumulator layout,
// fully coalesced uint2 stores + fp32 l. LDS 40KB -> 4 blocks/CU.
// ---------------------------------------------------------------------------
__global__ __launch_bounds__(256, 4) void attn_kernel(
    const unsigned short* __restrict__ Qbuf,
    const unsigned short* __restrict__ Kbuf,
    const unsigned short* __restrict__ Vtbuf,
    unsigned int* __restrict__ rawO,    // [rawblk][slot 32][lane 64] uint2
    float* __restrict__ Lraw)           // [rawblk][128]
{
    __shared__ unsigned short smem[20480];  // K dbuf 8192 | V dbuf 8192 | Ps 4096
    unsigned short* Kb = smem;              // [2][64*64] swizzled
    unsigned short* Vb = smem + 8192;       // [2][64*64] swizzled, [p][key]
    unsigned short* Ps = smem + 16384;      // [4 waves][16*64] swizzled

    const int tid = threadIdx.x;
    const int wv = tid >> 6;
    const int lane = tid & 63;
    const int g = lane >> 4;
    const int c16 = lane & 15;
    const int c8 = c16 & 7;
    const int split = blockIdx.z & 1;
    const int b = blockIdx.z >> 1;
    const int h = blockIdx.y;
    const int qt = blockIdx.x;
    const int q0 = qt * 128;

    // glds lane mapping: row-sub = lane>>3, phys chunk = lane&7,
    // logical chunk = (lane&7) ^ (row&7); row&7 == lane>>3 for 8-row blocks.
    const int lrow = lane >> 3;
    const int lcol = (((lane & 7) ^ lrow) * 8);   // shorts, logical col offset

    // ---- stage Q (128x64) into the K-dbuf region via glds (swizzled) ----
    const unsigned short* Qp = Qbuf + ((size_t)(b * NHEADS + h) * SEQQ + q0) * PDIM;
#pragma unroll
    for (int j = 0; j < 4; ++j) {
        int rowblk = (4 * wv + j) * 8;
        glds16(Qp + (size_t)(rowblk + lrow) * PDIM + lcol, smem + rowblk * 64);
    }
    __syncthreads();   // Q landed (vmcnt drained by barrier)

    short8 bQ[2][2];   // B[k=p][n=query=c16]; row R = 32wv+16y+c16, R&7 = c8
#pragma unroll
    for (int y = 0; y < 2; ++y)
#pragma unroll
        for (int ks = 0; ks < 2; ++ks)
            bQ[y][ks] = *(const short8*)(smem + (32 * wv + 16 * y + c16) * 64 +
                                         ((4 * ks + g) ^ c8) * 8);
    __syncthreads();   // all waves extracted Q before K glds overwrites region

    const unsigned short* Kp  = Kbuf  + (size_t)b * SEQK * PDIM + (size_t)split * 1024 * PDIM;
    const unsigned short* Vtp = Vtbuf + (size_t)b * PDIM * SEQK + split * 1024;

    // prologue: glds tile 0 -> buffer 0 (drained by first loop barrier)
#pragma unroll
    for (int j = 0; j < 2; ++j) {
        int rb = (2 * wv + j) * 8;
        glds16(Kp + (size_t)(rb + lrow) * PDIM + lcol, Kb + rb * 64);
        glds16(Vtp + (size_t)(rb + lrow) * SEQK + lcol, Vb + rb * 64);
    }

    f32x4 z = {0.f, 0.f, 0.f, 0.f};
    f32x4 oacc[2][4] = {{z, z, z, z}, {z, z, z, z}};
    float lsum[2] = {0.f, 0.f};
    unsigned short* PsW = Ps + wv * 1024;   // 16 x 64

    for (int i = 0; i < 16; ++i) {
        __syncthreads();   // drains glds(tile i); prev compute reads done
        const unsigned short* Kc = Kb + (i & 1) * 4096;
        const unsigned short* Vc = Vb + (i & 1) * 4096;
        if (i < 15) {      // prefetch tile i+1 into the other buffer (async)
            int t0 = (i + 1) * 64;
            unsigned short* Kn = Kb + ((i + 1) & 1) * 4096;
            unsigned short* Vn = Vb + ((i + 1) & 1) * 4096;
#pragma unroll
            for (int j = 0; j < 2; ++j) {
                int rb = (2 * wv + j) * 8;
                glds16(Kp + (size_t)(t0 + rb + lrow) * PDIM + lcol, Kn + rb * 64);
                glds16(Vtp + (size_t)(rb + lrow) * SEQK + t0 + lcol, Vn + rb * 64);
            }
        }

        // S^T = K_tile . Q^T : A[m=key] = K-frag (shared across strips)
        f32x4 s0a[4] = {z, z, z, z};
        f32x4 s1a[4] = {z, z, z, z};
#pragma unroll
        for (int ks = 0; ks < 2; ++ks) {
#pragma unroll
            for (int t = 0; t < 4; ++t) {
                short8 aK = *(const short8*)(Kc + (16 * t + c16) * 64 + ((4 * ks + g) ^ c8) * 8);
                s0a[t] = __builtin_amdgcn_mfma_f32_16x16x32_bf16(aK, bQ[0][ks], s0a[t], 0, 0, 0);
                s1a[t] = __builtin_amdgcn_mfma_f32_16x16x32_bf16(aK, bQ[1][ks], s1a[t], 0, 0, 0);
            }
        }

        // in-lane exp + sum; pack P to wave-private swizzled LDS (no barrier)
        short8 aP[2][2];
#pragma unroll
        for (int y = 0; y < 2; ++y) {
            const f32x4* sc = y ? s1a : s0a;
            float ls = 0.f;
#pragma unroll
            for (int t = 0; t < 4; ++t) {
                float p0 = __expf(sc[t][0]);
                float p1 = __expf(sc[t][1]);
                float p2 = __expf(sc[t][2]);
                float p3 = __expf(sc[t][3]);
                ls += (p0 + p1) + (p2 + p3);
                uint2 w2;
                w2.x = pack_bf16_rh(p0, p1);
                w2.y = pack_bf16_rh(p2, p3);
                int phys = (2 * t + (g >> 1)) ^ c8;
                *(uint2*)(PsW + c16 * 64 + phys * 8 + 4 * (g & 1)) = w2;
            }
            lsum[y] += ls;
#pragma unroll
            for (int ks = 0; ks < 2; ++ks)
                aP[y][ks] = *(const short8*)(PsW + c16 * 64 + ((4 * ks + g) ^ c8) * 8);
        }

        // O += P @ V : B[k=key][n=p] from Vt rows (shared across strips)
#pragma unroll
        for (int ks = 0; ks < 2; ++ks) {
#pragma unroll
            for (int u = 0; u < 4; ++u) {
                short8 bV = *(const short8*)(Vc + (16 * u + c16) * 64 + ((4 * ks + g) ^ c8) * 8);
                oacc[0][u] = __builtin_amdgcn_mfma_f32_16x16x32_bf16(aP[0][ks], bV, oacc[0][u], 0, 0, 0);
                oacc[1][u] = __builtin_amdgcn_mfma_f32_16x16x32_bf16(aP[1][ks], bV, oacc[1][u], 0, 0, 0);
            }
        }
    }

    // l lives split across the 4 g-lanes of each query column
#pragma unroll
    for (int y = 0; y < 2; ++y) {
        lsum[y] += __shfl_xor(lsum[y], 16);
        lsum[y] += __shfl_xor(lsum[y], 32);
    }

    // epilogue: raw accumulator-layout O (bf16 pairs over r), coalesced.
    const int rawblk = ((b * NHEADS + h) * 16 + qt) * 2 + split;
    unsigned int* rb = rawO + (size_t)rawblk * 4096;
#pragma unroll
    for (int y = 0; y < 2; ++y) {
#pragma unroll
        for (int u = 0; u < 4; ++u) {
            int slot = (wv * 2 + y) * 4 + u;
            uint2 w2;
            w2.x = pack_bf16_rh(oacc[y][u][0], oacc[y][u][1]);
            w2.y = pack_bf16_rh(oacc[y][u][2], oacc[y][u][3]);
            *(uint2*)(rb + slot * 128 + lane * 2) = w2;
        }
        if (g == 0)
            Lraw[(size_t)rawblk * 128 + 32 * wv + 16 * y + c16] = lsum[y];
    }
}

// ---------------------------------------------------------------------------
// Output projection FUSED with split-combine: out = concat(O/l) @ Wo + bo.
// grid = 64. Chunk c == head h: k-cols h*64..h*64+63 come from raw O of attn
// block (qt, h, b): combine splits + normalize during staging. No ctx buffer.
// ---------------------------------------------------------------------------
__global__ __launch_bounds__(256) void out_proj_kernel(
    const unsigned int* __restrict__ rawO, const float* __restrict__ Lraw,
    const unsigned short* __restrict__ Wt, const float* __restrict__ bo,
    float* __restrict__ out)
{
    __shared__ unsigned short XtS[128 * 72];
    __shared__ unsigned short WtS[64 * 72];

    const int tid = threadIdx.x;
    const int wv = tid >> 6, lane = tid & 63;
    const int g = lane >> 4, c16 = lane & 15;
    const int row0 = blockIdx.x * 128;
    const int b = row0 >> 11, qt = (row0 & 2047) >> 7;
    const unsigned short* W = Wt + (size_t)10 * 32768;

    f32x4 z = {0.f, 0.f, 0.f, 0.f};
    f32x4 acc[2][4] = {{z, z, z, z}, {z, z, z, z}};

    for (int h = 0; h < 8; ++h) {
        const int rb0 = ((b * 8 + h) * 16 + qt) * 2;
        const unsigned int* p0 = rawO + (size_t)rb0 * 4096;
        const unsigned int* p1 = rawO + (size_t)(rb0 + 1) * 4096;
        const float* l0 = Lraw + (size_t)rb0 * 128;
        const float* l1 = Lraw + (size_t)(rb0 + 1) * 128;

        float inv[2][4];
#pragma unroll
        for (int y = 0; y < 2; ++y)
#pragma unroll
            for (int r = 0; r < 4; ++r) {
                int q = 32 * wv + 16 * y + 4 * g + r;
                inv[y][r] = 1.0f / (l0[q] + l1[q]);
            }

        uint4 wreg[2];
#pragma unroll
        for (int it = 0; it < 2; ++it) {
            int flat = tid * 8 + 2048 * it;
            wreg[it] = *(const uint4*)(W + (size_t)(flat >> 6) * 512 + h * 64 + (flat & 63));
        }

        // combine + normalize into bf16 values (held in regs)
        unsigned short vv[2][4][4];
#pragma unroll
        for (int y = 0; y < 2; ++y)
#pragma unroll
            for (int u = 0; u < 4; ++u) {
                int slot = (wv * 2 + y) * 4 + u;
                uint2 a0 = *(const uint2*)(p0 + slot * 128 + lane * 2);
                uint2 a1 = *(const uint2*)(p1 + slot * 128 + lane * 2);
                vv[y][u][0] = f2bf((bf2f_lo(a0.x) + bf2f_lo(a1.x)) * inv[y][0]);
                vv[y][u][1] = f2bf((bf2f_hi(a0.x) + bf2f_hi(a1.x)) * inv[y][1]);
                vv[y][u][2] = f2bf((bf2f_lo(a0.y) + bf2f_lo(a1.y)) * inv[y][2]);
                vv[y][u][3] = f2bf((bf2f_hi(a0.y) + bf2f_hi(a1.y)) * inv[y][3]);
            }

        __syncthreads();   // previous chunk's MFMA reads done
#pragma unroll
        for (int it = 0; it < 2; ++it) {
            int flat = tid * 8 + 2048 * it;
            *(uint4*)(&WtS[(flat >> 6) * 72 + (flat & 63)]) = wreg[it];
        }
#pragma unroll
        for (int y = 0; y < 2; ++y)
#pragma unroll
            for (int u = 0; u < 4; ++u)
#pragma unroll
                for (int r = 0; r < 4; ++r)
                    XtS[(32 * wv + 16 * y + 4 * g + r) * 72 + 16 * u + c16] = vv[y][u][r];
        __syncthreads();

#pragma unroll
        for (int ks = 0; ks < 2; ++ks) {
            short8 aX[2];
#pragma unroll
            for (int y = 0; y < 2; ++y)
                aX[y] = *(const short8*)(&XtS[(32 * wv + 16 * y + c16) * 72 + 32 * ks + 8 * g]);
#pragma unroll
            for (int u = 0; u < 4; ++u) {
                short8 bW = *(const short8*)(&WtS[(16 * u + c16) * 72 + 32 * ks + 8 * g]);
                acc[0][u] = __builtin_amdgcn_mfma_f32_16x16x32_bf16(aX[0], bW, acc[0][u], 0, 0, 0);
                acc[1][u] = __builtin_amdgcn_mfma_f32_16x16x32_bf16(aX[1], bW, acc[1][u], 0, 0, 0);
            }
        }
    }

    float4 b4;
    b4.x = bo[16 * 0 + c16]; b4.y = bo[16 * 1 + c16];
    b4.z = bo[16 * 2 + c16]; b4.w = bo[16 * 3 + c16];
    float bb[4] = {b4.x, b4.y, b4.z, b4.w};
#pragma unroll
    for (int u = 0; u < 4; ++u)
#pragma unroll
        for (int y = 0; y < 2; ++y)
#pragma unroll
            for (int rr = 0; rr < 4; ++rr)
                out[(size_t)(row0 + 32 * wv + 16 * y + 4 * g + rr) * 64 + 16 * u + c16] =
                    acc[y][u][rr] + bb[u];
}

// ---------------------------------------------------------------------------
extern "C" void kernel_launch(void* const* d_in, const int* in_sizes, int n_in,
                              void* d_out, int out_size, void* d_ws, size_t ws_size,
                              hipStream_t stream) {
    const float* query = (const float*)d_in[0];
    const float* store = (const float*)d_in[1];
    const float* Wq    = (const float*)d_in[2];
    const float* bq    = (const float*)d_in[3];
    const float* Wk    = (const float*)d_in[4];
    const float* bk    = (const float*)d_in[5];
    const float* Wv    = (const float*)d_in[6];
    const float* bv    = (const float*)d_in[7];
    const float* Wo    = (const float*)d_in[8];
    const float* bo    = (const float*)d_in[9];
    float* out = (float*)d_out;

    // workspace (bf16 unless noted), with region reuse:
    // Xq|Xs [2 x 8192*512] -- consumed by qkv; REUSED as rawO (16 MB exactly)
    // Wt [11*32768] | Qbuf | Kbuf | Vt | Lraw (fp32 512KB)   total ~28.5 MiB
    unsigned short* Xq   = (unsigned short*)d_ws;
    unsigned short* Xs   = Xq + (size_t)8192 * 512;
    unsigned short* Wt   = Xs + (size_t)8192 * 512;
    unsigned short* Qbuf = Wt + (size_t)11 * 32768;
    unsigned short* Kbuf = Qbuf + (size_t)BATCH * NHEADS * SEQQ * PDIM;
    unsigned short* Vtbuf = Kbuf + (size_t)BATCH * SEQK * PDIM;
    float* Lraw          = (float*)(Vtbuf + (size_t)BATCH * PDIM * SEQK);
    unsigned int* rawO   = (unsigned int*)Xq;   // 1024 blocks x 16 KB = 16 MB

    convert_kernel<<<4096 + 176, 256, 0, stream>>>(query, store, Wq, Wk, Wv, Wo,
                                                   Xq, Xs, Wt);

    dim3 gProj((BATCH * SEQQ) / 128, NHEADS + 2);
    qkv_proj_kernel<<<gProj, 256, 0, stream>>>(Xq, Xs, Wt, bq, bk, bv,
                                               Qbuf, Kbuf, Vtbuf);

    dim3 gAttn(SEQQ / 128, NHEADS, BATCH * 2);
    attn_kernel<<<gAttn, 256, 0, stream>>>(Qbuf, Kbuf, Vtbuf, rawO, Lraw);

    out_proj_kernel<<<(BATCH * SEQQ) / 128, 256, 0, stream>>>(rawO, Lraw, Wt, bo, out);
}

// Round 8
// 213.902 us; speedup vs baseline: 1.3994x; 1.0636x over previous
//
#include <hip/hip_runtime.h>
#include <math.h>

// Problem constants (MultiQueryAttention_20229295964202)
#define BATCH   4
#define SEQQ    2048
#define SEQK    2048
#define DMODEL  512
#define NHEADS  8
#define PDIM    64

#define QSCALE  0.18033688f   // 0.125 * log2(e): scale folded into Q; exp2 in softmax

typedef __attribute__((ext_vector_type(8))) short short8;   // 8 bf16 (4 VGPRs)
typedef __attribute__((ext_vector_type(4))) float f32x4;    // MFMA C/D frag

__device__ __forceinline__ unsigned short f2bf(float x) {   // RNE
    unsigned u = __builtin_bit_cast(unsigned, x);
    u += 0x7fffu + ((u >> 16) & 1u);
    return (unsigned short)(u >> 16);
}
// pack two fp32 -> 2xbf16 in one dword, round-half-up
__device__ __forceinline__ unsigned pack_bf16_rh(float lo, float hi) {
    unsigned ul = __builtin_bit_cast(unsigned, lo) + 0x8000u;
    unsigned uh = __builtin_bit_cast(unsigned, hi) + 0x8000u;
    return __builtin_amdgcn_perm(uh, ul, 0x07060302u);  // [uh.hi16 : ul.hi16]
}
__device__ __forceinline__ float bf2f_lo(unsigned w) {
    return __builtin_bit_cast(float, w << 16);
}
__device__ __forceinline__ float bf2f_hi(unsigned w) {
    return __builtin_bit_cast(float, w & 0xFFFF0000u);
}
// raw v_exp_f32: D = 2^S0 (avoids glibc __exp2f name clash)
__device__ __forceinline__ float exp2_raw(float x) {
    return __builtin_amdgcn_exp2f(x);
}

// async global->LDS, 16B/lane; lds base is wave-uniform, HW adds lane*16
__device__ __forceinline__ void glds16(const unsigned short* g, unsigned short* l) {
    __builtin_amdgcn_global_load_lds(
        (const __attribute__((address_space(1))) void*)g,
        (__attribute__((address_space(3))) void*)l, 16, 0, 0);
}

// ---------------------------------------------------------------------------
// One-time conversion.
// Blocks 0..4095:   X fp32->bf16 (query pre-scaled by QSCALE).
// Blocks 4096..4106: weight transpose via LDS, one block per mat:
//   Wt[mat][n][k] bf16, coalesced uint4 stores (mat 0-7=Wq, 8=Wk, 9=Wv, 10=Wo)
// ---------------------------------------------------------------------------
__global__ __launch_bounds__(256) void convert_kernel(
    const float* __restrict__ query, const float* __restrict__ store,
    const float* __restrict__ Wq, const float* __restrict__ Wk,
    const float* __restrict__ Wv, const float* __restrict__ Wo,
    unsigned short* __restrict__ Xq, unsigned short* __restrict__ Xs,
    unsigned short* __restrict__ Wt)
{
    const int tid = threadIdx.x;
    const int blk = blockIdx.x;
    if (blk < 4096) {
        const float* src; unsigned short* dst; float sc; int idx;
        if (blk < 2048) { src = query; dst = Xq; sc = QSCALE; idx = (blk * 256 + tid) * 8; }
        else { src = store; dst = Xs; sc = 1.0f; idx = ((blk - 2048) * 256 + tid) * 8; }
        float4 a = *(const float4*)(src + idx);
        float4 b = *(const float4*)(src + idx + 4);
        ushort4 o0, o1;
        o0.x = f2bf(a.x * sc); o0.y = f2bf(a.y * sc);
        o0.z = f2bf(a.z * sc); o0.w = f2bf(a.w * sc);
        o1.x = f2bf(b.x * sc); o1.y = f2bf(b.y * sc);
        o1.z = f2bf(b.z * sc); o1.w = f2bf(b.w * sc);
        *(ushort4*)(dst + idx) = o0;
        *(ushort4*)(dst + idx + 4) = o1;
    } else {
        const int mat = blk - 4096;                // 0..10
        const float* src = (mat < 8) ? (Wq + (size_t)mat * 32768)
                         : (mat == 8) ? Wk : (mat == 9) ? Wv : Wo;
        __shared__ unsigned short T[64][72];       // [n][k], padded
        for (int k0 = 0; k0 < 512; k0 += 64) {
            // load 64k x 64n fp32, scatter-transpose into LDS
#pragma unroll
            for (int it = 0; it < 4; ++it) {
                int flat = tid * 4 + 1024 * it;    // k*64 + n
                int k = flat >> 6, n = flat & 63;
                float4 v = *(const float4*)(src + (size_t)(k0 + k) * 64 + n);
                T[n + 0][k] = f2bf(v.x);
                T[n + 1][k] = f2bf(v.y);
                T[n + 2][k] = f2bf(v.z);
                T[n + 3][k] = f2bf(v.w);
            }
            __syncthreads();
            // coalesced write: thread -> 16 shorts of one n-row
            int n = tid >> 2, kk = (tid & 3) * 16;
            uint4 w0 = *(const uint4*)(&T[n][kk]);
            uint4 w1 = *(const uint4*)(&T[n][kk + 8]);
            *(uint4*)(Wt + (size_t)mat * 32768 + (size_t)n * 512 + k0 + kk) = w0;
            *(uint4*)(Wt + (size_t)mat * 32768 + (size_t)n * 512 + k0 + kk + 8) = w1;
            __syncthreads();
        }
    }
}

// ---------------------------------------------------------------------------
// QKV projection, PAIRED mats: grid (64, 5). slot 0..3 -> Q heads (2s, 2s+1);
// slot 4 -> (K, V). 128-row x 128-col tiles: X staged once for both mats.
// ---------------------------------------------------------------------------
__global__ __launch_bounds__(256, 4) void qkv_proj_kernel(
    const unsigned short* __restrict__ Xq, const unsigned short* __restrict__ Xs,
    const unsigned short* __restrict__ Wt,
    const float* __restrict__ bq, const float* __restrict__ bk,
    const float* __restrict__ bv,
    unsigned short* __restrict__ Qbuf, unsigned short* __restrict__ Kbuf,
    unsigned short* __restrict__ Vtbuf)
{
    __shared__ unsigned short Xt[128 * 72];     // 18432 B
    __shared__ unsigned short Wtile[128 * 72];  // 18432 B  (rows 0-63 matA, 64-127 matB)

    const int slot = blockIdx.y;
    const int row0 = blockIdx.x * 128;
    const int b = row0 >> 11;
    const int s0 = row0 & 2047;
    const int matA = (slot < 4) ? 2 * slot : 8;

    const unsigned short* X = ((slot < 4) ? Xq : Xs) + (size_t)row0 * 512;
    const unsigned short* WA = Wt + (size_t)matA * 32768;
    const unsigned short* WB = WA + 32768;

    const int tid = threadIdx.x;
    const int wv = tid >> 6, lane = tid & 63;
    const int g = lane >> 4, c16 = lane & 15;

    f32x4 z = {0.f, 0.f, 0.f, 0.f};
    f32x4 acc[2][8] = {{z, z, z, z, z, z, z, z}, {z, z, z, z, z, z, z, z}};

    for (int k0 = 0; k0 < 512; k0 += 64) {
        uint4 xreg[4], wreg[4];
        int xr[4], xc[4];
#pragma unroll
        for (int it = 0; it < 4; ++it) {
            int flat = tid * 8 + 2048 * it;
            xr[it] = flat >> 6; xc[it] = flat & 63;
            xreg[it] = *(const uint4*)(X + (size_t)xr[it] * 512 + k0 + xc[it]);
        }
#pragma unroll
        for (int it = 0; it < 2; ++it) {
            int flat = tid * 8 + 2048 * it;
            wreg[it]     = *(const uint4*)(WA + (size_t)(flat >> 6) * 512 + k0 + (flat & 63));
            wreg[it + 2] = *(const uint4*)(WB + (size_t)(flat >> 6) * 512 + k0 + (flat & 63));
        }
        __syncthreads();   // previous chunk's MFMA reads done
#pragma unroll
        for (int it = 0; it < 4; ++it)
            *(uint4*)(&Xt[xr[it] * 72 + xc[it]]) = xreg[it];
#pragma unroll
        for (int it = 0; it < 2; ++it) {
            int flat = tid * 8 + 2048 * it;
            *(uint4*)(&Wtile[(flat >> 6) * 72 + (flat & 63)]) = wreg[it];
            *(uint4*)(&Wtile[(64 + (flat >> 6)) * 72 + (flat & 63)]) = wreg[it + 2];
        }
        __syncthreads();
#pragma unroll
        for (int ks = 0; ks < 2; ++ks) {
            short8 aX[2];
#pragma unroll
            for (int y = 0; y < 2; ++y)
                aX[y] = *(const short8*)(&Xt[(32 * wv + 16 * y + c16) * 72 + 32 * ks + 8 * g]);
#pragma unroll
            for (int u = 0; u < 8; ++u) {
                short8 bW = *(const short8*)(&Wtile[(16 * u + c16) * 72 + 32 * ks + 8 * g]);
                acc[0][u] = __builtin_amdgcn_mfma_f32_16x16x32_bf16(aX[0], bW, acc[0][u], 0, 0, 0);
                acc[1][u] = __builtin_amdgcn_mfma_f32_16x16x32_bf16(aX[1], bW, acc[1][u], 0, 0, 0);
            }
        }
    }

    if (slot < 4) {
        // two Q heads; Q pre-scaled by QSCALE (bias too)
#pragma unroll
        for (int m = 0; m < 2; ++m) {
            int head = 2 * slot + m;
            const float* bias = bq + head * 64;
            unsigned short* Y = Qbuf + ((size_t)(b * NHEADS + head) * SEQQ + s0) * PDIM;
#pragma unroll
            for (int uu = 0; uu < 4; ++uu) {
                float bb = QSCALE * bias[16 * uu + c16];
#pragma unroll
                for (int y = 0; y < 2; ++y)
#pragma unroll
                    for (int rr = 0; rr < 4; ++rr)
                        Y[(size_t)(32 * wv + 16 * y + 4 * g + rr) * PDIM + 16 * uu + c16] =
                            f2bf(acc[y][4 * m + uu][rr] + bb);
            }
        }
    } else {
        // matA = K (normal layout), matB = V (transposed)
        unsigned short* Yk = Kbuf + (size_t)row0 * PDIM;
#pragma unroll
        for (int uu = 0; uu < 4; ++uu) {
            float bb = bk[16 * uu + c16];
#pragma unroll
            for (int y = 0; y < 2; ++y)
#pragma unroll
                for (int rr = 0; rr < 4; ++rr)
                    Yk[(size_t)(32 * wv + 16 * y + 4 * g + rr) * PDIM + 16 * uu + c16] =
                        f2bf(acc[y][uu][rr] + bb);
        }
        unsigned short* Yv = Vtbuf + (size_t)b * PDIM * SEQK;
#pragma unroll
        for (int uu = 0; uu < 4; ++uu) {
            float bb = bv[16 * uu + c16];
#pragma unroll
            for (int y = 0; y < 2; ++y)
#pragma unroll
                for (int rr = 0; rr < 4; ++rr)
                    Yv[(size_t)(16 * uu + c16) * SEQK + s0 + 32 * wv + 16 * y + 4 * g + rr] =
                        f2bf(acc[y][4 + uu][rr] + bb);
        }
    }
}

// ---------------------------------------------------------------------------
// Flash attention, bf16 MFMA, S^T max-free softmax (exp2, scale pre-folded),
// K-SPLIT x2, glds double-buffered K/V, one barrier/iter (R6 structure).
// ---------------------------------------------------------------------------
__global__ __launch_bounds__(256, 4) void attn_kernel(
    const unsigned short* __restrict__ Qbuf,
    const unsigned short* __restrict__ Kbuf,
    const unsigned short* __restrict__ Vtbuf,
    unsigned int* __restrict__ rawO,    // [rawblk][slot 32][lane 64] uint2
    float* __restrict__ Lraw)           // [rawblk][128]
{
    __shared__ unsigned short smem[20480];  // K dbuf 8192 | V dbuf 8192 | Ps 4096
    unsigned short* Kb = smem;              // [2][64*64] swizzled
    unsigned short* Vb = smem + 8192;       // [2][64*64] swizzled, [p][key]
    unsigned short* Ps = smem + 16384;      // [4 waves][16*64] swizzled

    const int tid = threadIdx.x;
    const int wv = tid >> 6;
    const int lane = tid & 63;
    const int g = lane >> 4;
    const int c16 = lane & 15;
    const int c8 = c16 & 7;
    const int split = blockIdx.z & 1;
    const int b = blockIdx.z >> 1;
    const int h = blockIdx.y;
    const int qt = blockIdx.x;
    const int q0 = qt * 128;

    const int lrow = lane >> 3;
    const int lcol = (((lane & 7) ^ lrow) * 8);   // shorts, swizzled col offset

    // ---- stage Q (128x64) into the K-dbuf region via glds (swizzled) ----
    const unsigned short* Qp = Qbuf + ((size_t)(b * NHEADS + h) * SEQQ + q0) * PDIM;
#pragma unroll
    for (int j = 0; j < 4; ++j) {
        int rowblk = (4 * wv + j) * 8;
        glds16(Qp + (size_t)(rowblk + lrow) * PDIM + lcol, smem + rowblk * 64);
    }
    __syncthreads();   // Q landed

    short8 bQ[2][2];   // B[k=p][n=query=c16]
#pragma unroll
    for (int y = 0; y < 2; ++y)
#pragma unroll
        for (int ks = 0; ks < 2; ++ks)
            bQ[y][ks] = *(const short8*)(smem + (32 * wv + 16 * y + c16) * 64 +
                                         ((4 * ks + g) ^ c8) * 8);
    __syncthreads();   // all waves extracted Q before K glds overwrites region

    const unsigned short* Kp  = Kbuf  + (size_t)b * SEQK * PDIM + (size_t)split * 1024 * PDIM;
    const unsigned short* Vtp = Vtbuf + (size_t)b * PDIM * SEQK + split * 1024;

    // prologue: glds tile 0 -> buffer 0
#pragma unroll
    for (int j = 0; j < 2; ++j) {
        int rb = (2 * wv + j) * 8;
        glds16(Kp + (size_t)(rb + lrow) * PDIM + lcol, Kb + rb * 64);
        glds16(Vtp + (size_t)(rb + lrow) * SEQK + lcol, Vb + rb * 64);
    }

    f32x4 z = {0.f, 0.f, 0.f, 0.f};
    f32x4 oacc[2][4] = {{z, z, z, z}, {z, z, z, z}};
    float lsum[2] = {0.f, 0.f};
    unsigned short* PsW = Ps + wv * 1024;   // 16 x 64

    for (int i = 0; i < 16; ++i) {
        __syncthreads();   // drains glds(tile i); prev compute reads done
        const unsigned short* Kc = Kb + (i & 1) * 4096;
        const unsigned short* Vc = Vb + (i & 1) * 4096;
        if (i < 15) {      // prefetch tile i+1 into the other buffer (async)
            int t0 = (i + 1) * 64;
            unsigned short* Kn = Kb + ((i + 1) & 1) * 4096;
            unsigned short* Vn = Vb + ((i + 1) & 1) * 4096;
#pragma unroll
            for (int j = 0; j < 2; ++j) {
                int rb = (2 * wv + j) * 8;
                glds16(Kp + (size_t)(t0 + rb + lrow) * PDIM + lcol, Kn + rb * 64);
                glds16(Vtp + (size_t)(rb + lrow) * SEQK + t0 + lcol, Vn + rb * 64);
            }
        }

        // S^T = K_tile . Q^T : A[m=key] = K-frag (shared across strips)
        f32x4 s0a[4] = {z, z, z, z};
        f32x4 s1a[4] = {z, z, z, z};
#pragma unroll
        for (int ks = 0; ks < 2; ++ks) {
#pragma unroll
            for (int t = 0; t < 4; ++t) {
                short8 aK = *(const short8*)(Kc + (16 * t + c16) * 64 + ((4 * ks + g) ^ c8) * 8);
                s0a[t] = __builtin_amdgcn_mfma_f32_16x16x32_bf16(aK, bQ[0][ks], s0a[t], 0, 0, 0);
                s1a[t] = __builtin_amdgcn_mfma_f32_16x16x32_bf16(aK, bQ[1][ks], s1a[t], 0, 0, 0);
            }
        }

        // in-lane exp2 + sum; pack P to wave-private swizzled LDS (no barrier)
        short8 aP[2][2];
#pragma unroll
        for (int y = 0; y < 2; ++y) {
            const f32x4* sc = y ? s1a : s0a;
            float ls = 0.f;
#pragma unroll
            for (int t = 0; t < 4; ++t) {
                float p0 = exp2_raw(sc[t][0]);
                float p1 = exp2_raw(sc[t][1]);
                float p2 = exp2_raw(sc[t][2]);
                float p3 = exp2_raw(sc[t][3]);
                ls += (p0 + p1) + (p2 + p3);
                uint2 w2;
                w2.x = pack_bf16_rh(p0, p1);
                w2.y = pack_bf16_rh(p2, p3);
                int phys = (2 * t + (g >> 1)) ^ c8;
                *(uint2*)(PsW + c16 * 64 + phys * 8 + 4 * (g & 1)) = w2;
            }
            lsum[y] += ls;
#pragma unroll
            for (int ks = 0; ks < 2; ++ks)
                aP[y][ks] = *(const short8*)(PsW + c16 * 64 + ((4 * ks + g) ^ c8) * 8);
        }

        // O += P @ V : B[k=key][n=p] from Vt rows (shared across strips)
#pragma unroll
        for (int ks = 0; ks < 2; ++ks) {
#pragma unroll
            for (int u = 0; u < 4; ++u) {
                short8 bV = *(const short8*)(Vc + (16 * u + c16) * 64 + ((4 * ks + g) ^ c8) * 8);
                oacc[0][u] = __builtin_amdgcn_mfma_f32_16x16x32_bf16(aP[0][ks], bV, oacc[0][u], 0, 0, 0);
                oacc[1][u] = __builtin_amdgcn_mfma_f32_16x16x32_bf16(aP[1][ks], bV, oacc[1][u], 0, 0, 0);
            }
        }
    }

    // l lives split across the 4 g-lanes of each query column
#pragma unroll
    for (int y = 0; y < 2; ++y) {
        lsum[y] += __shfl_xor(lsum[y], 16);
        lsum[y] += __shfl_xor(lsum[y], 32);
    }

    // epilogue: raw accumulator-layout O (bf16 pairs over r), coalesced.
    const int rawblk = ((b * NHEADS + h) * 16 + qt) * 2 + split;
    unsigned int* rb = rawO + (size_t)rawblk * 4096;
#pragma unroll
    for (int y = 0; y < 2; ++y) {
#pragma unroll
        for (int u = 0; u < 4; ++u) {
            int slot = (wv * 2 + y) * 4 + u;
            uint2 w2;
            w2.x = pack_bf16_rh(oacc[y][u][0], oacc[y][u][1]);
            w2.y = pack_bf16_rh(oacc[y][u][2], oacc[y][u][3]);
            *(uint2*)(rb + slot * 128 + lane * 2) = w2;
        }
        if (g == 0)
            Lraw[(size_t)rawblk * 128 + 32 * wv + 16 * y + c16] = lsum[y];
    }
}

// ---------------------------------------------------------------------------
// Output projection FUSED with split-combine: out = concat(O/l) @ Wo + bo.
// grid = 128 blocks, 64-row tiles (2x parallelism vs R6).
// ---------------------------------------------------------------------------
__global__ __launch_bounds__(256) void out_proj_kernel(
    const unsigned int* __restrict__ rawO, const float* __restrict__ Lraw,
    const unsigned short* __restrict__ Wt, const float* __restrict__ bo,
    float* __restrict__ out)
{
    __shared__ unsigned short XtS[64 * 72];
    __shared__ unsigned short WtS[64 * 72];

    const int tid = threadIdx.x;
    const int wv = tid >> 6, lane = tid & 63;
    const int g = lane >> 4, c16 = lane & 15;
    const int row0 = blockIdx.x * 64;
    const int b = row0 >> 11;
    const int qt = (row0 & 2047) >> 7;
    const int off = row0 & 127;            // 0 or 64 within the attn 128-tile
    const unsigned short* W = Wt + (size_t)10 * 32768;

    f32x4 z = {0.f, 0.f, 0.f, 0.f};
    f32x4 acc[4] = {z, z, z, z};

    for (int h = 0; h < 8; ++h) {
        const int rb0 = ((b * 8 + h) * 16 + qt) * 2;
        const unsigned int* p0 = rawO + (size_t)rb0 * 4096;
        const unsigned int* p1 = rawO + (size_t)(rb0 + 1) * 4096;
        const float* l0 = Lraw + (size_t)rb0 * 128;
        const float* l1 = Lraw + (size_t)(rb0 + 1) * 128;

        float inv[4];
#pragma unroll
        for (int r = 0; r < 4; ++r) {
            int q = off + 16 * wv + 4 * g + r;
            inv[r] = 1.0f / (l0[q] + l1[q]);
        }

        uint4 wreg[2];
#pragma unroll
        for (int it = 0; it < 2; ++it) {
            int flat = tid * 8 + 2048 * it;
            wreg[it] = *(const uint4*)(W + (size_t)(flat >> 6) * 512 + h * 64 + (flat & 63));
        }

        // combine + normalize into bf16 values (held briefly in regs)
        unsigned short vv[4][4];
        const int sbase = ((off + 16 * wv) >> 4) * 4;   // attn slot base for this wave
#pragma unroll
        for (int u = 0; u < 4; ++u) {
            uint2 a0 = *(const uint2*)(p0 + (sbase + u) * 128 + lane * 2);
            uint2 a1 = *(const uint2*)(p1 + (sbase + u) * 128 + lane * 2);
            vv[u][0] = f2bf((bf2f_lo(a0.x) + bf2f_lo(a1.x)) * inv[0]);
            vv[u][1] = f2bf((bf2f_hi(a0.x) + bf2f_hi(a1.x)) * inv[1]);
            vv[u][2] = f2bf((bf2f_lo(a0.y) + bf2f_lo(a1.y)) * inv[2]);
            vv[u][3] = f2bf((bf2f_hi(a0.y) + bf2f_hi(a1.y)) * inv[3]);
        }

        __syncthreads();   // previous chunk's MFMA reads done
#pragma unroll
        for (int it = 0; it < 2; ++it) {
            int flat = tid * 8 + 2048 * it;
            *(uint4*)(&WtS[(flat >> 6) * 72 + (flat & 63)]) = wreg[it];
        }
#pragma unroll
        for (int u = 0; u < 4; ++u)
#pragma unroll
            for (int r = 0; r < 4; ++r)
                XtS[(16 * wv + 4 * g + r) * 72 + 16 * u + c16] = vv[u][r];
        __syncthreads();

#pragma unroll
        for (int ks = 0; ks < 2; ++ks) {
            short8 aX = *(const short8*)(&XtS[(16 * wv + c16) * 72 + 32 * ks + 8 * g]);
#pragma unroll
            for (int u = 0; u < 4; ++u) {
                short8 bW = *(const short8*)(&WtS[(16 * u + c16) * 72 + 32 * ks + 8 * g]);
                acc[u] = __builtin_amdgcn_mfma_f32_16x16x32_bf16(aX, bW, acc[u], 0, 0, 0);
            }
        }
    }

    float bb[4];
#pragma unroll
    for (int u = 0; u < 4; ++u) bb[u] = bo[16 * u + c16];
#pragma unroll
    for (int u = 0; u < 4; ++u)
#pragma unroll
        for (int rr = 0; rr < 4; ++rr)
            out[(size_t)(row0 + 16 * wv + 4 * g + rr) * 64 + 16 * u + c16] =
                acc[u][rr] + bb[u];
}

// ---------------------------------------------------------------------------
extern "C" void kernel_launch(void* const* d_in, const int* in_sizes, int n_in,
                              void* d_out, int out_size, void* d_ws, size_t ws_size,
                              hipStream_t stream) {
    const float* query = (const float*)d_in[0];
    const float* store = (const float*)d_in[1];
    const float* Wq    = (const float*)d_in[2];
    const float* bq    = (const float*)d_in[3];
    const float* Wk    = (const float*)d_in[4];
    const float* bk    = (const float*)d_in[5];
    const float* Wv    = (const float*)d_in[6];
    const float* bv    = (const float*)d_in[7];
    const float* Wo    = (const float*)d_in[8];
    const float* bo    = (const float*)d_in[9];
    float* out = (float*)d_out;

    // workspace (bf16 unless noted), with region reuse:
    // Xq|Xs [2 x 8192*512] -- consumed by qkv; REUSED as rawO (16 MB exactly)
    // Wt [11*32768] | Qbuf | Kbuf | Vt | Lraw (fp32 512KB)   total ~28.5 MiB
    unsigned short* Xq   = (unsigned short*)d_ws;
    unsigned short* Xs   = Xq + (size_t)8192 * 512;
    unsigned short* Wt   = Xs + (size_t)8192 * 512;
    unsigned short* Qbuf = Wt + (size_t)11 * 32768;
    unsigned short* Kbuf = Qbuf + (size_t)BATCH * NHEADS * SEQQ * PDIM;
    unsigned short* Vtbuf = Kbuf + (size_t)BATCH * SEQK * PDIM;
    float* Lraw          = (float*)(Vtbuf + (size_t)BATCH * PDIM * SEQK);
    unsigned int* rawO   = (unsigned int*)Xq;   // 1024 blocks x 16 KB = 16 MB

    convert_kernel<<<4096 + 11, 256, 0, stream>>>(query, store, Wq, Wk, Wv, Wo,
                                                  Xq, Xs, Wt);

    dim3 gProj((BATCH * SEQQ) / 128, 5);
    qkv_proj_kernel<<<gProj, 256, 0, stream>>>(Xq, Xs, Wt, bq, bk, bv,
                                               Qbuf, Kbuf, Vtbuf);

    dim3 gAttn(SEQQ / 128, NHEADS, BATCH * 2);
    attn_kernel<<<gAttn, 256, 0, stream>>>(Qbuf, Kbuf, Vtbuf, rawO, Lraw);

    out_proj_kernel<<<(BATCH * SEQQ) / 64, 256, 0, stream>>>(rawO, Lraw, Wt, bo, out);
}

// Round 9
// 179.560 us; speedup vs baseline: 1.6670x; 1.1913x over previous
//
#include <hip/hip_runtime.h>
#include <math.h>

// Problem constants (MultiQueryAttention_20229295964202)
#define BATCH   4
#define SEQQ    2048
#define SEQK    2048
#define DMODEL  512
#define NHEADS  8
#define PDIM    64

#define QSCALE  0.18033688f   // 0.125 * log2(e); folded into Wq/bq; exp2 softmax

typedef __attribute__((ext_vector_type(8))) short short8;   // 8 bf16 (4 VGPRs)
typedef __attribute__((ext_vector_type(4))) float f32x4;    // MFMA C/D frag

__device__ __forceinline__ unsigned short f2bf(float x) {   // RNE
    unsigned u = __builtin_bit_cast(unsigned, x);
    u += 0x7fffu + ((u >> 16) & 1u);
    return (unsigned short)(u >> 16);
}
__device__ __forceinline__ unsigned pack_bf16_rh(float lo, float hi) {
    unsigned ul = __builtin_bit_cast(unsigned, lo) + 0x8000u;
    unsigned uh = __builtin_bit_cast(unsigned, hi) + 0x8000u;
    return __builtin_amdgcn_perm(uh, ul, 0x07060302u);  // [uh.hi16 : ul.hi16]
}
__device__ __forceinline__ float bf2f_lo(unsigned w) {
    return __builtin_bit_cast(float, w << 16);
}
__device__ __forceinline__ float bf2f_hi(unsigned w) {
    return __builtin_bit_cast(float, w & 0xFFFF0000u);
}
__device__ __forceinline__ float exp2_raw(float x) {        // raw v_exp_f32
    return __builtin_amdgcn_exp2f(x);
}
// async global->LDS, 16B/lane; lds base is wave-uniform, HW adds lane*16
__device__ __forceinline__ void glds16(const void* g, void* l) {
    __builtin_amdgcn_global_load_lds(
        (const __attribute__((address_space(1))) void*)g,
        (__attribute__((address_space(3))) void*)l, 16, 0, 0);
}

// ---------------------------------------------------------------------------
// Weight transpose only: Wt[mat][n][k] bf16 (mat 0-7=Wq*QSCALE, 8=Wk, 9=Wv,
// 10=Wo). 11 blocks.
// ---------------------------------------------------------------------------
__global__ __launch_bounds__(256) void convert_w_kernel(
    const float* __restrict__ Wq, const float* __restrict__ Wk,
    const float* __restrict__ Wv, const float* __restrict__ Wo,
    unsigned short* __restrict__ Wt)
{
    const int tid = threadIdx.x;
    const int mat = blockIdx.x;                // 0..10
    const float sc = (mat < 8) ? QSCALE : 1.0f;
    const float* src = (mat < 8) ? (Wq + (size_t)mat * 32768)
                     : (mat == 8) ? Wk : (mat == 9) ? Wv : Wo;
    __shared__ unsigned short T[64][72];       // [n][k-sub], padded
    for (int k0 = 0; k0 < 512; k0 += 64) {
#pragma unroll
        for (int it = 0; it < 4; ++it) {
            int flat = tid * 4 + 1024 * it;    // k*64 + n
            int k = flat >> 6, n = flat & 63;
            float4 v = *(const float4*)(src + (size_t)(k0 + k) * 64 + n);
            T[n + 0][k] = f2bf(v.x * sc);
            T[n + 1][k] = f2bf(v.y * sc);
            T[n + 2][k] = f2bf(v.z * sc);
            T[n + 3][k] = f2bf(v.w * sc);
        }
        __syncthreads();
        int n = tid >> 2, kk = (tid & 3) * 16;
        uint4 w0 = *(const uint4*)(&T[n][kk]);
        uint4 w1 = *(const uint4*)(&T[n][kk + 8]);
        *(uint4*)(Wt + (size_t)mat * 32768 + (size_t)n * 512 + k0 + kk) = w0;
        *(uint4*)(Wt + (size_t)mat * 32768 + (size_t)n * 512 + k0 + kk + 8) = w1;
        __syncthreads();
    }
}

// ---------------------------------------------------------------------------
// QKV projection reading fp32 X directly (cvt in staging). Paired mats:
// grid (128, 5): slot 0..3 -> Q heads (2s,2s+1); slot 4 -> (K, V).
// 64-row x 128-col tiles; W via swizzled glds (pair rows are contiguous in Wt).
// V^T epilogue via LDS transpose -> coalesced uint4 stores (no write amp).
// ---------------------------------------------------------------------------
__global__ __launch_bounds__(256, 4) void qkv_proj_kernel(
    const float* __restrict__ query, const float* __restrict__ store_,
    const unsigned short* __restrict__ Wt,
    const float* __restrict__ bq, const float* __restrict__ bk,
    const float* __restrict__ bv,
    unsigned short* __restrict__ Qbuf, unsigned short* __restrict__ Kbuf,
    unsigned short* __restrict__ Vtbuf)
{
    __shared__ unsigned short Xt[64 * 72];      //  9216 B (stride 72)
    __shared__ unsigned short Wtile[128 * 64];  // 16384 B (stride 64, XOR swizzle)

    const int slot = blockIdx.y;
    const int row0 = blockIdx.x * 64;
    const int b = row0 >> 11;
    const int s0 = row0 & 2047;
    const int matA = (slot < 4) ? 2 * slot : 8;

    const float* X = ((slot < 4) ? query : store_) + (size_t)row0 * 512;
    const unsigned short* WA = Wt + (size_t)matA * 32768;  // 128 rows (pair)

    const int tid = threadIdx.x;
    const int wv = tid >> 6, lane = tid & 63;
    const int g = lane >> 4, c16 = lane & 15;
    const int c8 = c16 & 7;
    const int lrow = lane >> 3;
    const int lcol = ((lane & 7) ^ lrow) * 8;   // swizzled col (shorts)

    f32x4 z = {0.f, 0.f, 0.f, 0.f};
    f32x4 acc[8] = {z, z, z, z, z, z, z, z};

    const int xcol = (tid & 15) * 4;
    for (int k0 = 0; k0 < 512; k0 += 64) {
        float4 xr[4];
        int xrow[4];
#pragma unroll
        for (int it = 0; it < 4; ++it) {
            xrow[it] = (tid >> 4) + 16 * it;
            xr[it] = *(const float4*)(X + (size_t)xrow[it] * 512 + k0 + xcol);
        }
        __syncthreads();   // prev chunk's MFMA reads of Xt/Wtile done
        // glds W pair tile (128 rows x 64 k), swizzled
#pragma unroll
        for (int j = 0; j < 4; ++j) {
            int rb = (4 * wv + j) * 8;
            glds16(WA + (size_t)(rb + lrow) * 512 + k0 + lcol, Wtile + rb * 64);
        }
        // X cvt + LDS store
#pragma unroll
        for (int it = 0; it < 4; ++it) {
            ushort4 o;
            o.x = f2bf(xr[it].x); o.y = f2bf(xr[it].y);
            o.z = f2bf(xr[it].z); o.w = f2bf(xr[it].w);
            *(ushort4*)(&Xt[xrow[it] * 72 + xcol]) = o;
        }
        __syncthreads();   // drains glds + lds stores
#pragma unroll
        for (int ks = 0; ks < 2; ++ks) {
            short8 aX = *(const short8*)(&Xt[(16 * wv + c16) * 72 + 32 * ks + 8 * g]);
#pragma unroll
            for (int u = 0; u < 8; ++u) {
                short8 bW = *(const short8*)(Wtile + (16 * u + c16) * 64 + ((4 * ks + g) ^ c8) * 8);
                acc[u] = __builtin_amdgcn_mfma_f32_16x16x32_bf16(aX, bW, acc[u], 0, 0, 0);
            }
        }
    }

    if (slot < 4) {
#pragma unroll
        for (int m = 0; m < 2; ++m) {
            int head = 2 * slot + m;
            const float* bias = bq + head * 64;
            unsigned short* Y = Qbuf + ((size_t)(b * NHEADS + head) * SEQQ + s0) * PDIM;
#pragma unroll
            for (int uu = 0; uu < 4; ++uu) {
                float bb = QSCALE * bias[16 * uu + c16];
#pragma unroll
                for (int rr = 0; rr < 4; ++rr)
                    Y[(size_t)(16 * wv + 4 * g + rr) * PDIM + 16 * uu + c16] =
                        f2bf(acc[4 * m + uu][rr] + bb);
            }
        }
    } else {
        // K (acc 0..3): normal layout
        unsigned short* Yk = Kbuf + (size_t)row0 * PDIM;
#pragma unroll
        for (int uu = 0; uu < 4; ++uu) {
            float bb = bk[16 * uu + c16];
#pragma unroll
            for (int rr = 0; rr < 4; ++rr)
                Yk[(size_t)(16 * wv + 4 * g + rr) * PDIM + 16 * uu + c16] =
                    f2bf(acc[uu][rr] + bb);
        }
        // V (acc 4..7): LDS transpose -> coalesced stores to Vt[p][s]
        __syncthreads();   // all MFMA reads done; reuse Xt as Vlds[64p][72]
#pragma unroll
        for (int uu = 0; uu < 4; ++uu) {
            float bb = bv[16 * uu + c16];
#pragma unroll
            for (int rr = 0; rr < 4; ++rr)
                Xt[(16 * uu + c16) * 72 + (16 * wv + 4 * g + rr)] =
                    f2bf(acc[4 + uu][rr] + bb);
        }
        __syncthreads();
        int p = tid >> 2, soff = (tid & 3) * 16;
        uint4 w0 = *(const uint4*)(&Xt[p * 72 + soff]);
        uint4 w1 = *(const uint4*)(&Xt[p * 72 + soff + 8]);
        unsigned short* dst = Vtbuf + (size_t)b * PDIM * SEQK + (size_t)p * SEQK + s0 + soff;
        *(uint4*)(dst) = w0;
        *(uint4*)(dst + 8) = w1;
    }
}

// ---------------------------------------------------------------------------
// Flash attention, bf16 MFMA, S^T max-free softmax (exp2), K-SPLIT x2,
// glds double-buffered K/V, one barrier/iter. l accumulated via MFMA with a
// constant ones B-frag (replaces VALU sum tree + shuffles; result lands in
// C-layout, matching the O rows exactly).
// ---------------------------------------------------------------------------
__global__ __launch_bounds__(256, 4) void attn_kernel(
    const unsigned short* __restrict__ Qbuf,
    const unsigned short* __restrict__ Kbuf,
    const unsigned short* __restrict__ Vtbuf,
    unsigned int* __restrict__ rawO,    // [rawblk][slot 32][lane 64] uint2
    float* __restrict__ Lraw)           // [rawblk][128]
{
    __shared__ unsigned short smem[20480];  // K dbuf 8192 | V dbuf 8192 | Ps 4096
    unsigned short* Kb = smem;
    unsigned short* Vb = smem + 8192;
    unsigned short* Ps = smem + 16384;

    const int tid = threadIdx.x;
    const int wv = tid >> 6;
    const int lane = tid & 63;
    const int g = lane >> 4;
    const int c16 = lane & 15;
    const int c8 = c16 & 7;
    const int split = blockIdx.z & 1;
    const int b = blockIdx.z >> 1;
    const int h = blockIdx.y;
    const int qt = blockIdx.x;
    const int q0 = qt * 128;

    const int lrow = lane >> 3;
    const int lcol = ((lane & 7) ^ lrow) * 8;

    // stage Q (128x64) into the K-dbuf region via glds (swizzled)
    const unsigned short* Qp = Qbuf + ((size_t)(b * NHEADS + h) * SEQQ + q0) * PDIM;
#pragma unroll
    for (int j = 0; j < 4; ++j) {
        int rowblk = (4 * wv + j) * 8;
        glds16(Qp + (size_t)(rowblk + lrow) * PDIM + lcol, smem + rowblk * 64);
    }
    __syncthreads();

    short8 bQ[2][2];   // B[k=p][n=query=c16]
#pragma unroll
    for (int y = 0; y < 2; ++y)
#pragma unroll
        for (int ks = 0; ks < 2; ++ks)
            bQ[y][ks] = *(const short8*)(smem + (32 * wv + 16 * y + c16) * 64 +
                                         ((4 * ks + g) ^ c8) * 8);
    __syncthreads();

    const unsigned short* Kp  = Kbuf  + (size_t)b * SEQK * PDIM + (size_t)split * 1024 * PDIM;
    const unsigned short* Vtp = Vtbuf + (size_t)b * PDIM * SEQK + split * 1024;

#pragma unroll
    for (int j = 0; j < 2; ++j) {
        int rb = (2 * wv + j) * 8;
        glds16(Kp + (size_t)(rb + lrow) * PDIM + lcol, Kb + rb * 64);
        glds16(Vtp + (size_t)(rb + lrow) * SEQK + lcol, Vb + rb * 64);
    }

    const short one_bf = (short)0x3F80;   // bf16 1.0
    short8 vones = {one_bf, one_bf, one_bf, one_bf, one_bf, one_bf, one_bf, one_bf};

    f32x4 z = {0.f, 0.f, 0.f, 0.f};
    f32x4 oacc[2][4] = {{z, z, z, z}, {z, z, z, z}};
    f32x4 lacc[2] = {z, z};
    unsigned short* PsW = Ps + wv * 1024;   // 16 x 64

    for (int i = 0; i < 16; ++i) {
        __syncthreads();   // drains glds(tile i); prev compute reads done
        const unsigned short* Kc = Kb + (i & 1) * 4096;
        const unsigned short* Vc = Vb + (i & 1) * 4096;
        if (i < 15) {
            int t0 = (i + 1) * 64;
            unsigned short* Kn = Kb + ((i + 1) & 1) * 4096;
            unsigned short* Vn = Vb + ((i + 1) & 1) * 4096;
#pragma unroll
            for (int j = 0; j < 2; ++j) {
                int rb = (2 * wv + j) * 8;
                glds16(Kp + (size_t)(t0 + rb + lrow) * PDIM + lcol, Kn + rb * 64);
                glds16(Vtp + (size_t)(rb + lrow) * SEQK + t0 + lcol, Vn + rb * 64);
            }
        }

        // S^T = K_tile . Q^T
        f32x4 s0a[4] = {z, z, z, z};
        f32x4 s1a[4] = {z, z, z, z};
#pragma unroll
        for (int ks = 0; ks < 2; ++ks) {
#pragma unroll
            for (int t = 0; t < 4; ++t) {
                short8 aK = *(const short8*)(Kc + (16 * t + c16) * 64 + ((4 * ks + g) ^ c8) * 8);
                s0a[t] = __builtin_amdgcn_mfma_f32_16x16x32_bf16(aK, bQ[0][ks], s0a[t], 0, 0, 0);
                s1a[t] = __builtin_amdgcn_mfma_f32_16x16x32_bf16(aK, bQ[1][ks], s1a[t], 0, 0, 0);
            }
        }

        // in-lane exp2; pack P to wave-private swizzled LDS (no sum tree)
        short8 aP[2][2];
#pragma unroll
        for (int y = 0; y < 2; ++y) {
            const f32x4* sc = y ? s1a : s0a;
#pragma unroll
            for (int t = 0; t < 4; ++t) {
                float p0 = exp2_raw(sc[t][0]);
                float p1 = exp2_raw(sc[t][1]);
                float p2 = exp2_raw(sc[t][2]);
                float p3 = exp2_raw(sc[t][3]);
                uint2 w2;
                w2.x = pack_bf16_rh(p0, p1);
                w2.y = pack_bf16_rh(p2, p3);
                int phys = (2 * t + (g >> 1)) ^ c8;
                *(uint2*)(PsW + c16 * 64 + phys * 8 + 4 * (g & 1)) = w2;
            }
#pragma unroll
            for (int ks = 0; ks < 2; ++ks)
                aP[y][ks] = *(const short8*)(PsW + c16 * 64 + ((4 * ks + g) ^ c8) * 8);
        }

        // O += P @ V ; l += P @ ones (MFMA does the row sums)
#pragma unroll
        for (int ks = 0; ks < 2; ++ks) {
            lacc[0] = __builtin_amdgcn_mfma_f32_16x16x32_bf16(aP[0][ks], vones, lacc[0], 0, 0, 0);
            lacc[1] = __builtin_amdgcn_mfma_f32_16x16x32_bf16(aP[1][ks], vones, lacc[1], 0, 0, 0);
#pragma unroll
            for (int u = 0; u < 4; ++u) {
                short8 bV = *(const short8*)(Vc + (16 * u + c16) * 64 + ((4 * ks + g) ^ c8) * 8);
                oacc[0][u] = __builtin_amdgcn_mfma_f32_16x16x32_bf16(aP[0][ks], bV, oacc[0][u], 0, 0, 0);
                oacc[1][u] = __builtin_amdgcn_mfma_f32_16x16x32_bf16(aP[1][ks], bV, oacc[1][u], 0, 0, 0);
            }
        }
    }

    // epilogue: raw accumulator-layout O (bf16 pairs over r), coalesced;
    // l per row is directly lacc[y][r] (C-layout rows 4g+r, all cols equal).
    const int rawblk = ((b * NHEADS + h) * 16 + qt) * 2 + split;
    unsigned int* rb = rawO + (size_t)rawblk * 4096;
#pragma unroll
    for (int y = 0; y < 2; ++y) {
#pragma unroll
        for (int u = 0; u < 4; ++u) {
            int slot = (wv * 2 + y) * 4 + u;
            uint2 w2;
            w2.x = pack_bf16_rh(oacc[y][u][0], oacc[y][u][1]);
            w2.y = pack_bf16_rh(oacc[y][u][2], oacc[y][u][3]);
            *(uint2*)(rb + slot * 128 + lane * 2) = w2;
        }
        if (c16 == 0) {
#pragma unroll
            for (int r = 0; r < 4; ++r)
                Lraw[(size_t)rawblk * 128 + 32 * wv + 16 * y + 4 * g + r] = lacc[y][r];
        }
    }
}

// ---------------------------------------------------------------------------
// Output projection fused with split-combine: out = concat(O/l) @ Wo + bo.
// 32-row tiles -> grid 256 (all CUs); TWO heads per k-chunk -> 4 chunks.
// Wave w: MFMA strip sm=w&1 (rows 16sm..), u-half uh=w>>1 (cols 32uh..).
// ---------------------------------------------------------------------------
__global__ __launch_bounds__(256) void out_proj_kernel(
    const unsigned int* __restrict__ rawO, const float* __restrict__ Lraw,
    const unsigned short* __restrict__ Wt, const float* __restrict__ bo,
    float* __restrict__ out)
{
    __shared__ unsigned short XtS[32 * 136];   //  8704 B
    __shared__ unsigned short WtS[64 * 136];   // 17408 B

    const int tid = threadIdx.x;
    const int wv = tid >> 6, lane = tid & 63;
    const int g = lane >> 4, c16 = lane & 15;
    const int row0 = blockIdx.x * 32;
    const int b = row0 >> 11;
    const int qt = (row0 & 2047) >> 7;
    const int off = row0 & 127;                // 0/32/64/96 within attn 128-tile
    const unsigned short* W = Wt + (size_t)10 * 32768;

    const int sm = wv & 1;      // MFMA row strip
    const int uh = wv >> 1;     // u-half (u = 2uh, 2uh+1)

    f32x4 z = {0.f, 0.f, 0.f, 0.f};
    f32x4 acc[2] = {z, z};

    for (int ch = 0; ch < 4; ++ch) {
        const int h0 = 2 * ch;
        // W loads (64 n-rows x 128 k = 2 heads)
        uint4 wreg[4];
        int wrow[4], wkk[4];
#pragma unroll
        for (int it = 0; it < 4; ++it) {
            int flat = tid * 8 + 2048 * it;
            wrow[it] = flat >> 7; wkk[it] = flat & 127;
            int hh = wkk[it] >> 6;
            wreg[it] = *(const uint4*)(W + (size_t)wrow[it] * 512 + (h0 + hh) * 64 + (wkk[it] & 63));
        }
        // rawO combine: wave stages local slots 2wv, 2wv+1 for both heads
        unsigned short vv[2][2][4];   // [hh][sl][r]
#pragma unroll
        for (int hh = 0; hh < 2; ++hh) {
            int h = h0 + hh;
            int rb0 = ((b * NHEADS + h) * 16 + qt) * 2;
            const unsigned int* p0 = rawO + (size_t)rb0 * 4096;
            const unsigned int* p1 = rawO + (size_t)(rb0 + 1) * 4096;
            const float* l0 = Lraw + (size_t)rb0 * 128;
            const float* l1 = Lraw + (size_t)(rb0 + 1) * 128;
#pragma unroll
            for (int sl = 0; sl < 2; ++sl) {
                int s_local = 2 * wv + sl;
                int m = s_local >> 2, u = s_local & 3;
                int sglob = ((off >> 4) + m) * 4 + u;
                uint2 a0 = *(const uint2*)(p0 + sglob * 128 + lane * 2);
                uint2 a1 = *(const uint2*)(p1 + sglob * 128 + lane * 2);
                float iv[4];
#pragma unroll
                for (int r = 0; r < 4; ++r) {
                    int q = off + 16 * m + 4 * g + r;
                    iv[r] = 1.0f / (l0[q] + l1[q]);
                }
                vv[hh][sl][0] = f2bf((bf2f_lo(a0.x) + bf2f_lo(a1.x)) * iv[0]);
                vv[hh][sl][1] = f2bf((bf2f_hi(a0.x) + bf2f_hi(a1.x)) * iv[1]);
                vv[hh][sl][2] = f2bf((bf2f_lo(a0.y) + bf2f_lo(a1.y)) * iv[2]);
                vv[hh][sl][3] = f2bf((bf2f_hi(a0.y) + bf2f_hi(a1.y)) * iv[3]);
            }
        }
        __syncthreads();   // prev chunk's MFMA reads done
#pragma unroll
        for (int it = 0; it < 4; ++it)
            *(uint4*)(&WtS[wrow[it] * 136 + wkk[it]]) = wreg[it];
#pragma unroll
        for (int hh = 0; hh < 2; ++hh)
#pragma unroll
            for (int sl = 0; sl < 2; ++sl) {
                int s_local = 2 * wv + sl;
                int m = s_local >> 2, u = s_local & 3;
#pragma unroll
                for (int r = 0; r < 4; ++r)
                    XtS[(16 * m + 4 * g + r) * 136 + hh * 64 + 16 * u + c16] = vv[hh][sl][r];
            }
        __syncthreads();

#pragma unroll
        for (int hh = 0; hh < 2; ++hh)
#pragma unroll
            for (int ks = 0; ks < 2; ++ks) {
                short8 aX = *(const short8*)(&XtS[(16 * sm + c16) * 136 + hh * 64 + 32 * ks + 8 * g]);
#pragma unroll
                for (int uu = 0; uu < 2; ++uu) {
                    int u = 2 * uh + uu;
                    short8 bW = *(const short8*)(&WtS[(16 * u + c16) * 136 + hh * 64 + 32 * ks + 8 * g]);
                    acc[uu] = __builtin_amdgcn_mfma_f32_16x16x32_bf16(aX, bW, acc[uu], 0, 0, 0);
                }
            }
    }

#pragma unroll
    for (int uu = 0; uu < 2; ++uu) {
        int u = 2 * uh + uu;
        float bb = bo[16 * u + c16];
#pragma unroll
        for (int r = 0; r < 4; ++r)
            out[(size_t)(row0 + 16 * sm + 4 * g + r) * 64 + 16 * u + c16] = acc[uu][r] + bb;
    }
}

// ---------------------------------------------------------------------------
extern "C" void kernel_launch(void* const* d_in, const int* in_sizes, int n_in,
                              void* d_out, int out_size, void* d_ws, size_t ws_size,
                              hipStream_t stream) {
    const float* query = (const float*)d_in[0];
    const float* store_ = (const float*)d_in[1];
    const float* Wq    = (const float*)d_in[2];
    const float* bq    = (const float*)d_in[3];
    const float* Wk    = (const float*)d_in[4];
    const float* bk    = (const float*)d_in[5];
    const float* Wv    = (const float*)d_in[6];
    const float* bv    = (const float*)d_in[7];
    const float* Wo    = (const float*)d_in[8];
    const float* bo    = (const float*)d_in[9];
    float* out = (float*)d_out;

    // workspace: Wt 0.7MB | Qbuf 8MB | Kbuf 1MB | Vt 1MB | rawO 16MB | Lraw 0.5MB
    unsigned short* Wt   = (unsigned short*)d_ws;
    unsigned short* Qbuf = Wt + (size_t)11 * 32768;
    unsigned short* Kbuf = Qbuf + (size_t)BATCH * NHEADS * SEQQ * PDIM;
    unsigned short* Vtbuf = Kbuf + (size_t)BATCH * SEQK * PDIM;
    unsigned int* rawO   = (unsigned int*)(Vtbuf + (size_t)BATCH * PDIM * SEQK);
    float* Lraw          = (float*)(rawO + (size_t)1024 * 4096);

    convert_w_kernel<<<11, 256, 0, stream>>>(Wq, Wk, Wv, Wo, Wt);

    dim3 gProj((BATCH * SEQQ) / 64, 5);
    qkv_proj_kernel<<<gProj, 256, 0, stream>>>(query, store_, Wt, bq, bk, bv,
                                               Qbuf, Kbuf, Vtbuf);

    dim3 gAttn(SEQQ / 128, NHEADS, BATCH * 2);
    attn_kernel<<<gAttn, 256, 0, stream>>>(Qbuf, Kbuf, Vtbuf, rawO, Lraw);

    out_proj_kernel<<<(BATCH * SEQQ) / 32, 256, 0, stream>>>(rawO, Lraw, Wt, bo, out);
}

// Round 10
// 166.944 us; speedup vs baseline: 1.7930x; 1.0756x over previous
//
#include <hip/hip_runtime.h>
#include <math.h>

// Problem constants (MultiQueryAttention_20229295964202)
#define BATCH   4
#define SEQQ    2048
#define SEQK    2048
#define DMODEL  512
#define NHEADS  8
#define PDIM    64

#define QSCALE  0.18033688f   // 0.125 * log2(e); folded into Wq/bq; exp2 softmax

typedef __attribute__((ext_vector_type(8))) short short8;   // 8 bf16 (4 VGPRs)
typedef __attribute__((ext_vector_type(4))) float f32x4;    // MFMA C/D frag

__device__ __forceinline__ unsigned short f2bf(float x) {   // RNE
    unsigned u = __builtin_bit_cast(unsigned, x);
    u += 0x7fffu + ((u >> 16) & 1u);
    return (unsigned short)(u >> 16);
}
__device__ __forceinline__ unsigned pack_bf16_rh(float lo, float hi) {
    unsigned ul = __builtin_bit_cast(unsigned, lo) + 0x8000u;
    unsigned uh = __builtin_bit_cast(unsigned, hi) + 0x8000u;
    return __builtin_amdgcn_perm(uh, ul, 0x07060302u);  // [uh.hi16 : ul.hi16]
}
__device__ __forceinline__ float bf2f_lo(unsigned w) {
    return __builtin_bit_cast(float, w << 16);
}
__device__ __forceinline__ float bf2f_hi(unsigned w) {
    return __builtin_bit_cast(float, w & 0xFFFF0000u);
}
__device__ __forceinline__ float exp2_raw(float x) {        // raw v_exp_f32
    return __builtin_amdgcn_exp2f(x);
}
// async global->LDS, 16B/lane; lds base is wave-uniform, HW adds lane*16
__device__ __forceinline__ void glds16(const void* g, void* l) {
    __builtin_amdgcn_global_load_lds(
        (const __attribute__((address_space(1))) void*)g,
        (__attribute__((address_space(3))) void*)l, 16, 0, 0);
}

// ---------------------------------------------------------------------------
// Weight transpose: Wt[mat][n][k] bf16 (mat 0-7=Wq*QSCALE, 8=Wk, 9=Wv, 10=Wo).
// grid 88 = (mat, k-chunk): no serial loop.
// ---------------------------------------------------------------------------
__global__ __launch_bounds__(256) void convert_w_kernel(
    const float* __restrict__ Wq, const float* __restrict__ Wk,
    const float* __restrict__ Wv, const float* __restrict__ Wo,
    unsigned short* __restrict__ Wt)
{
    const int tid = threadIdx.x;
    const int mat = blockIdx.x >> 3;           // 0..10
    const int k0 = (blockIdx.x & 7) << 6;      // 0..448
    const float sc = (mat < 8) ? QSCALE : 1.0f;
    const float* src = (mat < 8) ? (Wq + (size_t)mat * 32768)
                     : (mat == 8) ? Wk : (mat == 9) ? Wv : Wo;
    __shared__ unsigned short T[64][72];       // [n][k-sub], padded
#pragma unroll
    for (int it = 0; it < 4; ++it) {
        int flat = tid * 4 + 1024 * it;        // k*64 + n
        int k = flat >> 6, n = flat & 63;
        float4 v = *(const float4*)(src + (size_t)(k0 + k) * 64 + n);
        T[n + 0][k] = f2bf(v.x * sc);
        T[n + 1][k] = f2bf(v.y * sc);
        T[n + 2][k] = f2bf(v.z * sc);
        T[n + 3][k] = f2bf(v.w * sc);
    }
    __syncthreads();
    int n = tid >> 2, kk = (tid & 3) * 16;
    uint4 w0 = *(const uint4*)(&T[n][kk]);
    uint4 w1 = *(const uint4*)(&T[n][kk + 8]);
    *(uint4*)(Wt + (size_t)mat * 32768 + (size_t)n * 512 + k0 + kk) = w0;
    *(uint4*)(Wt + (size_t)mat * 32768 + (size_t)n * 512 + k0 + kk + 8) = w1;
}

// ---------------------------------------------------------------------------
// QKV projection, fp32 X read directly (cvt in staging). 32-row x 256-col
// tiles; grid (256, 3): slot 0 = heads 0-3, slot 1 = heads 4-7 (query read
// 2x not 4x), slot 2 = K|V (128 cols). W via swizzled glds (L2-resident).
// Wave (sm = wv&1, uh = wv>>1): rows 16sm.., col-half uh.
// ---------------------------------------------------------------------------
__global__ __launch_bounds__(256, 4) void qkv_proj_kernel(
    const float* __restrict__ query, const float* __restrict__ store_,
    const unsigned short* __restrict__ Wt,
    const float* __restrict__ bq, const float* __restrict__ bk,
    const float* __restrict__ bv,
    unsigned short* __restrict__ Qbuf, unsigned short* __restrict__ Kbuf,
    unsigned short* __restrict__ Vtbuf)
{
    __shared__ unsigned short Xt[2560];         // X tile [32][72] / Vlds [64][40]
    __shared__ unsigned short Wtile[256 * 64];  // 32768 B, XOR swizzle

    const int slot = blockIdx.y;
    const int row0 = blockIdx.x * 32;
    const int b = row0 >> 11;
    const int s0 = row0 & 2047;

    const float* X = ((slot < 2) ? query : store_) + (size_t)row0 * 512;
    const unsigned short* Wbase = Wt + (size_t)(slot * 4) * 32768;  // slot2 -> mats 8,9

    const int tid = threadIdx.x;
    const int wv = tid >> 6, lane = tid & 63;
    const int g = lane >> 4, c16 = lane & 15;
    const int c8 = c16 & 7;
    const int sm = wv & 1;
    const int uh = wv >> 1;
    const int lrow = lane >> 3;
    const int lcol = ((lane & 7) ^ lrow) * 8;   // swizzled col (shorts)

    f32x4 z = {0.f, 0.f, 0.f, 0.f};
    f32x4 acc[8] = {z, z, z, z, z, z, z, z};

    const int xrow = tid >> 3;                  // 0..31
    const int xcol = (tid & 7) * 8;             // 0..56
    const int nwr = (slot < 2) ? 8 : 4;         // W row-blocks per wave

    for (int k0 = 0; k0 < 512; k0 += 64) {
        float4 xa = *(const float4*)(X + (size_t)xrow * 512 + k0 + xcol);
        float4 xb = *(const float4*)(X + (size_t)xrow * 512 + k0 + xcol + 4);
        __syncthreads();   // prev chunk's MFMA reads of Xt/Wtile done
        for (int j = 0; j < nwr; ++j) {
            int rb = (nwr * wv + j) * 8;
            glds16(Wbase + (size_t)(rb + lrow) * 512 + k0 + lcol, Wtile + rb * 64);
        }
        ushort4 o0, o1;
        o0.x = f2bf(xa.x); o0.y = f2bf(xa.y); o0.z = f2bf(xa.z); o0.w = f2bf(xa.w);
        o1.x = f2bf(xb.x); o1.y = f2bf(xb.y); o1.z = f2bf(xb.z); o1.w = f2bf(xb.w);
        *(ushort4*)(&Xt[xrow * 72 + xcol]) = o0;
        *(ushort4*)(&Xt[xrow * 72 + xcol + 4]) = o1;
        __syncthreads();   // drains glds + lds stores

        if (slot < 2) {
#pragma unroll
            for (int ks = 0; ks < 2; ++ks) {
                short8 aX = *(const short8*)(&Xt[(16 * sm + c16) * 72 + 32 * ks + 8 * g]);
#pragma unroll
                for (int uu = 0; uu < 8; ++uu) {
                    int u = 8 * uh + uu;
                    short8 bW = *(const short8*)(Wtile + (16 * u + c16) * 64 + ((4 * ks + g) ^ c8) * 8);
                    acc[uu] = __builtin_amdgcn_mfma_f32_16x16x32_bf16(aX, bW, acc[uu], 0, 0, 0);
                }
            }
        } else {
#pragma unroll
            for (int ks = 0; ks < 2; ++ks) {
                short8 aX = *(const short8*)(&Xt[(16 * sm + c16) * 72 + 32 * ks + 8 * g]);
#pragma unroll
                for (int uu = 0; uu < 4; ++uu) {
                    int u = 4 * uh + uu;
                    short8 bW = *(const short8*)(Wtile + (16 * u + c16) * 64 + ((4 * ks + g) ^ c8) * 8);
                    acc[uu] = __builtin_amdgcn_mfma_f32_16x16x32_bf16(aX, bW, acc[uu], 0, 0, 0);
                }
            }
        }
    }

    if (slot < 2) {
        // 4 Q heads; wave uh covers heads 2uh, 2uh+1 of this slot
#pragma unroll
        for (int uu = 0; uu < 8; ++uu) {
            int u = 8 * uh + uu;
            int head = 4 * slot + (u >> 2);
            int pc = 16 * (u & 3) + c16;
            float bb = QSCALE * bq[head * 64 + pc];
            unsigned short* Y = Qbuf + ((size_t)(b * NHEADS + head) * SEQQ + s0) * PDIM;
#pragma unroll
            for (int r = 0; r < 4; ++r)
                Y[(size_t)(16 * sm + 4 * g + r) * PDIM + pc] = f2bf(acc[uu][r] + bb);
        }
    } else {
        // uh==0 waves hold K (u 0..3); uh==1 waves hold V (u 4..7)
        if (uh == 0) {
            unsigned short* Yk = Kbuf + (size_t)row0 * PDIM;
#pragma unroll
            for (int uu = 0; uu < 4; ++uu) {
                float bb = bk[16 * uu + c16];
#pragma unroll
                for (int r = 0; r < 4; ++r)
                    Yk[(size_t)(16 * sm + 4 * g + r) * PDIM + 16 * uu + c16] =
                        f2bf(acc[uu][r] + bb);
            }
        }
        __syncthreads();   // Xt MFMA reads done; reuse as Vlds[64][40]
        if (uh == 1) {
#pragma unroll
            for (int uu = 0; uu < 4; ++uu) {
                int p = 16 * uu + c16;
                float bb = bv[p];
#pragma unroll
                for (int r = 0; r < 4; ++r)
                    Xt[p * 40 + 16 * sm + 4 * g + r] = f2bf(acc[uu][r] + bb);
            }
        }
        __syncthreads();
        int p = tid >> 2, soff = (tid & 3) * 8;
        uint4 w = *(const uint4*)(&Xt[p * 40 + soff]);
        *(uint4*)(Vtbuf + (size_t)b * PDIM * SEQK + (size_t)p * SEQK + s0 + soff) = w;
    }
}

// ---------------------------------------------------------------------------
// Flash attention (R9, unchanged): bf16 MFMA, S^T max-free softmax (exp2),
// K-SPLIT x2, glds double-buffered K/V, one barrier/iter, l via MFMA ones.
// ---------------------------------------------------------------------------
__global__ __launch_bounds__(256, 4) void attn_kernel(
    const unsigned short* __restrict__ Qbuf,
    const unsigned short* __restrict__ Kbuf,
    const unsigned short* __restrict__ Vtbuf,
    unsigned int* __restrict__ rawO,    // [rawblk][slot 32][lane 64] uint2
    float* __restrict__ Lraw)           // [rawblk][128]
{
    __shared__ unsigned short smem[20480];  // K dbuf 8192 | V dbuf 8192 | Ps 4096
    unsigned short* Kb = smem;
    unsigned short* Vb = smem + 8192;
    unsigned short* Ps = smem + 16384;

    const int tid = threadIdx.x;
    const int wv = tid >> 6;
    const int lane = tid & 63;
    const int g = lane >> 4;
    const int c16 = lane & 15;
    const int c8 = c16 & 7;
    const int split = blockIdx.z & 1;
    const int b = blockIdx.z >> 1;
    const int h = blockIdx.y;
    const int qt = blockIdx.x;
    const int q0 = qt * 128;

    const int lrow = lane >> 3;
    const int lcol = ((lane & 7) ^ lrow) * 8;

    const unsigned short* Qp = Qbuf + ((size_t)(b * NHEADS + h) * SEQQ + q0) * PDIM;
#pragma unroll
    for (int j = 0; j < 4; ++j) {
        int rowblk = (4 * wv + j) * 8;
        glds16(Qp + (size_t)(rowblk + lrow) * PDIM + lcol, smem + rowblk * 64);
    }
    __syncthreads();

    short8 bQ[2][2];   // B[k=p][n=query=c16]
#pragma unroll
    for (int y = 0; y < 2; ++y)
#pragma unroll
        for (int ks = 0; ks < 2; ++ks)
            bQ[y][ks] = *(const short8*)(smem + (32 * wv + 16 * y + c16) * 64 +
                                         ((4 * ks + g) ^ c8) * 8);
    __syncthreads();

    const unsigned short* Kp  = Kbuf  + (size_t)b * SEQK * PDIM + (size_t)split * 1024 * PDIM;
    const unsigned short* Vtp = Vtbuf + (size_t)b * PDIM * SEQK + split * 1024;

#pragma unroll
    for (int j = 0; j < 2; ++j) {
        int rb = (2 * wv + j) * 8;
        glds16(Kp + (size_t)(rb + lrow) * PDIM + lcol, Kb + rb * 64);
        glds16(Vtp + (size_t)(rb + lrow) * SEQK + lcol, Vb + rb * 64);
    }

    const short one_bf = (short)0x3F80;   // bf16 1.0
    short8 vones = {one_bf, one_bf, one_bf, one_bf, one_bf, one_bf, one_bf, one_bf};

    f32x4 z = {0.f, 0.f, 0.f, 0.f};
    f32x4 oacc[2][4] = {{z, z, z, z}, {z, z, z, z}};
    f32x4 lacc[2] = {z, z};
    unsigned short* PsW = Ps + wv * 1024;   // 16 x 64

    for (int i = 0; i < 16; ++i) {
        __syncthreads();   // drains glds(tile i); prev compute reads done
        const unsigned short* Kc = Kb + (i & 1) * 4096;
        const unsigned short* Vc = Vb + (i & 1) * 4096;
        if (i < 15) {
            int t0 = (i + 1) * 64;
            unsigned short* Kn = Kb + ((i + 1) & 1) * 4096;
            unsigned short* Vn = Vb + ((i + 1) & 1) * 4096;
#pragma unroll
            for (int j = 0; j < 2; ++j) {
                int rb = (2 * wv + j) * 8;
                glds16(Kp + (size_t)(t0 + rb + lrow) * PDIM + lcol, Kn + rb * 64);
                glds16(Vtp + (size_t)(rb + lrow) * SEQK + t0 + lcol, Vn + rb * 64);
            }
        }

        // S^T = K_tile . Q^T
        f32x4 s0a[4] = {z, z, z, z};
        f32x4 s1a[4] = {z, z, z, z};
#pragma unroll
        for (int ks = 0; ks < 2; ++ks) {
#pragma unroll
            for (int t = 0; t < 4; ++t) {
                short8 aK = *(const short8*)(Kc + (16 * t + c16) * 64 + ((4 * ks + g) ^ c8) * 8);
                s0a[t] = __builtin_amdgcn_mfma_f32_16x16x32_bf16(aK, bQ[0][ks], s0a[t], 0, 0, 0);
                s1a[t] = __builtin_amdgcn_mfma_f32_16x16x32_bf16(aK, bQ[1][ks], s1a[t], 0, 0, 0);
            }
        }

        // in-lane exp2; pack P to wave-private swizzled LDS
        short8 aP[2][2];
#pragma unroll
        for (int y = 0; y < 2; ++y) {
            const f32x4* sc = y ? s1a : s0a;
#pragma unroll
            for (int t = 0; t < 4; ++t) {
                float p0 = exp2_raw(sc[t][0]);
                float p1 = exp2_raw(sc[t][1]);
                float p2 = exp2_raw(sc[t][2]);
                float p3 = exp2_raw(sc[t][3]);
                uint2 w2;
                w2.x = pack_bf16_rh(p0, p1);
                w2.y = pack_bf16_rh(p2, p3);
                int phys = (2 * t + (g >> 1)) ^ c8;
                *(uint2*)(PsW + c16 * 64 + phys * 8 + 4 * (g & 1)) = w2;
            }
#pragma unroll
            for (int ks = 0; ks < 2; ++ks)
                aP[y][ks] = *(const short8*)(PsW + c16 * 64 + ((4 * ks + g) ^ c8) * 8);
        }

        // O += P @ V ; l += P @ ones
#pragma unroll
        for (int ks = 0; ks < 2; ++ks) {
            lacc[0] = __builtin_amdgcn_mfma_f32_16x16x32_bf16(aP[0][ks], vones, lacc[0], 0, 0, 0);
            lacc[1] = __builtin_amdgcn_mfma_f32_16x16x32_bf16(aP[1][ks], vones, lacc[1], 0, 0, 0);
#pragma unroll
            for (int u = 0; u < 4; ++u) {
                short8 bV = *(const short8*)(Vc + (16 * u + c16) * 64 + ((4 * ks + g) ^ c8) * 8);
                oacc[0][u] = __builtin_amdgcn_mfma_f32_16x16x32_bf16(aP[0][ks], bV, oacc[0][u], 0, 0, 0);
                oacc[1][u] = __builtin_amdgcn_mfma_f32_16x16x32_bf16(aP[1][ks], bV, oacc[1][u], 0, 0, 0);
            }
        }
    }

    const int rawblk = ((b * NHEADS + h) * 16 + qt) * 2 + split;
    unsigned int* rb = rawO + (size_t)rawblk * 4096;
#pragma unroll
    for (int y = 0; y < 2; ++y) {
#pragma unroll
        for (int u = 0; u < 4; ++u) {
            int slot = (wv * 2 + y) * 4 + u;
            uint2 w2;
            w2.x = pack_bf16_rh(oacc[y][u][0], oacc[y][u][1]);
            w2.y = pack_bf16_rh(oacc[y][u][2], oacc[y][u][3]);
            *(uint2*)(rb + slot * 128 + lane * 2) = w2;
        }
        if (c16 == 0) {
#pragma unroll
            for (int r = 0; r < 4; ++r)
                Lraw[(size_t)rawblk * 128 + 32 * wv + 16 * y + 4 * g + r] = lacc[y][r];
        }
    }
}

// ---------------------------------------------------------------------------
// Output projection fused with split-combine: out = concat(O/l) @ Wo + bo.
// 32-row tiles, grid 256; TWO chunks of FOUR heads each (4 barriers total).
// Wave (sm = wv&1, uh = wv>>1): rows 16sm.., n-tiles u = 2uh, 2uh+1.
// ---------------------------------------------------------------------------
__global__ __launch_bounds__(256) void out_proj_kernel(
    const unsigned int* __restrict__ rawO, const float* __restrict__ Lraw,
    const unsigned short* __restrict__ Wt, const float* __restrict__ bo,
    float* __restrict__ out)
{
    __shared__ unsigned short XtS[32 * 264];   // 16896 B
    __shared__ unsigned short WtS[64 * 264];   // 33792 B

    const int tid = threadIdx.x;
    const int wv = tid >> 6, lane = tid & 63;
    const int g = lane >> 4, c16 = lane & 15;
    const int row0 = blockIdx.x * 32;
    const int b = row0 >> 11;
    const int qt = (row0 & 2047) >> 7;
    const int off = row0 & 127;                // 0/32/64/96 within attn 128-tile
    const unsigned short* W = Wt + (size_t)10 * 32768;

    const int sm = wv & 1;
    const int uh = wv >> 1;

    f32x4 z = {0.f, 0.f, 0.f, 0.f};
    f32x4 acc[2] = {z, z};

    for (int ch = 0; ch < 2; ++ch) {
        const int h0 = 4 * ch;
        // W loads: 64 n-rows x 256 k (4 heads, contiguous within each row)
        uint4 wreg[8];
        int wrow[8], wkk[8];
#pragma unroll
        for (int it = 0; it < 8; ++it) {
            int flat = tid * 8 + 2048 * it;
            wrow[it] = flat >> 8; wkk[it] = flat & 255;
            wreg[it] = *(const uint4*)(W + (size_t)wrow[it] * 512 + h0 * 64 + wkk[it]);
        }
        // rawO combine: per head hh, wave stages local slots 2wv, 2wv+1
        unsigned short vv[4][2][4];   // [hh][sl][r]
#pragma unroll
        for (int hh = 0; hh < 4; ++hh) {
            int h = h0 + hh;
            int rb0 = ((b * NHEADS + h) * 16 + qt) * 2;
            const unsigned int* p0 = rawO + (size_t)rb0 * 4096;
            const unsigned int* p1 = rawO + (size_t)(rb0 + 1) * 4096;
            const float* l0 = Lraw + (size_t)rb0 * 128;
            const float* l1 = Lraw + (size_t)(rb0 + 1) * 128;
#pragma unroll
            for (int sl = 0; sl < 2; ++sl) {
                int s_local = 2 * wv + sl;
                int m = s_local >> 2, u = s_local & 3;
                int sglob = ((off >> 4) + m) * 4 + u;
                uint2 a0 = *(const uint2*)(p0 + sglob * 128 + lane * 2);
                uint2 a1 = *(const uint2*)(p1 + sglob * 128 + lane * 2);
                float iv[4];
#pragma unroll
                for (int r = 0; r < 4; ++r) {
                    int q = off + 16 * m + 4 * g + r;
                    iv[r] = 1.0f / (l0[q] + l1[q]);
                }
                vv[hh][sl][0] = f2bf((bf2f_lo(a0.x) + bf2f_lo(a1.x)) * iv[0]);
                vv[hh][sl][1] = f2bf((bf2f_hi(a0.x) + bf2f_hi(a1.x)) * iv[1]);
                vv[hh][sl][2] = f2bf((bf2f_lo(a0.y) + bf2f_lo(a1.y)) * iv[2]);
                vv[hh][sl][3] = f2bf((bf2f_hi(a0.y) + bf2f_hi(a1.y)) * iv[3]);
            }
        }
        __syncthreads();   // prev chunk's MFMA reads done
#pragma unroll
        for (int it = 0; it < 8; ++it)
            *(uint4*)(&WtS[wrow[it] * 264 + wkk[it]]) = wreg[it];
#pragma unroll
        for (int hh = 0; hh < 4; ++hh)
#pragma unroll
            for (int sl = 0; sl < 2; ++sl) {
                int s_local = 2 * wv + sl;
                int m = s_local >> 2, u = s_local & 3;
#pragma unroll
                for (int r = 0; r < 4; ++r)
                    XtS[(16 * m + 4 * g + r) * 264 + hh * 64 + 16 * u + c16] = vv[hh][sl][r];
            }
        __syncthreads();

#pragma unroll
        for (int hh = 0; hh < 4; ++hh)
#pragma unroll
            for (int ks = 0; ks < 2; ++ks) {
                short8 aX = *(const short8*)(&XtS[(16 * sm + c16) * 264 + hh * 64 + 32 * ks + 8 * g]);
#pragma unroll
                for (int uu = 0; uu < 2; ++uu) {
                    int u = 2 * uh + uu;
                    short8 bW = *(const short8*)(&WtS[(16 * u + c16) * 264 + hh * 64 + 32 * ks + 8 * g]);
                    acc[uu] = __builtin_amdgcn_mfma_f32_16x16x32_bf16(aX, bW, acc[uu], 0, 0, 0);
                }
            }
    }

#pragma unroll
    for (int uu = 0; uu < 2; ++uu) {
        int u = 2 * uh + uu;
        float bb = bo[16 * u + c16];
#pragma unroll
        for (int r = 0; r < 4; ++r)
            out[(size_t)(row0 + 16 * sm + 4 * g + r) * 64 + 16 * u + c16] = acc[uu][r] + bb;
    }
}

// ---------------------------------------------------------------------------
extern "C" void kernel_launch(void* const* d_in, const int* in_sizes, int n_in,
                              void* d_out, int out_size, void* d_ws, size_t ws_size,
                              hipStream_t stream) {
    const float* query  = (const float*)d_in[0];
    const float* store_ = (const float*)d_in[1];
    const float* Wq     = (const float*)d_in[2];
    const float* bq     = (const float*)d_in[3];
    const float* Wk     = (const float*)d_in[4];
    const float* bk     = (const float*)d_in[5];
    const float* Wv     = (const float*)d_in[6];
    const float* bv     = (const float*)d_in[7];
    const float* Wo     = (const float*)d_in[8];
    const float* bo     = (const float*)d_in[9];
    float* out = (float*)d_out;

    // workspace: Wt 0.7MB | Qbuf 8MB | Kbuf 1MB | Vt 1MB | rawO 16MB | Lraw 0.5MB
    unsigned short* Wt   = (unsigned short*)d_ws;
    unsigned short* Qbuf = Wt + (size_t)11 * 32768;
    unsigned short* Kbuf = Qbuf + (size_t)BATCH * NHEADS * SEQQ * PDIM;
    unsigned short* Vtbuf = Kbuf + (size_t)BATCH * SEQK * PDIM;
    unsigned int* rawO   = (unsigned int*)(Vtbuf + (size_t)BATCH * PDIM * SEQK);
    float* Lraw          = (float*)(rawO + (size_t)1024 * 4096);

    convert_w_kernel<<<88, 256, 0, stream>>>(Wq, Wk, Wv, Wo, Wt);

    dim3 gProj((BATCH * SEQQ) / 32, 3);
    qkv_proj_kernel<<<gProj, 256, 0, stream>>>(query, store_, Wt, bq, bk, bv,
                                               Qbuf, Kbuf, Vtbuf);

    dim3 gAttn(SEQQ / 128, NHEADS, BATCH * 2);
    attn_kernel<<<gAttn, 256, 0, stream>>>(Qbuf, Kbuf, Vtbuf, rawO, Lraw);

    out_proj_kernel<<<(BATCH * SEQQ) / 32, 256, 0, stream>>>(rawO, Lraw, Wt, bo, out);
}